// Round 12
// baseline (445.806 us; speedup 1.0000x reference)
//
#include <hip/hip_runtime.h>
#include <cstdint>
#include <cstddef>

constexpr int kN = 50000;
constexpr float kSlope = 0.2f;
constexpr float kBnEps = 1e-5f;

static inline int ceil_div(int a, int b) { return (a + b - 1) / b; }

typedef __attribute__((ext_vector_type(8))) _Float16 half8;
typedef __attribute__((ext_vector_type(8))) unsigned short ushortx8;
typedef __attribute__((ext_vector_type(4))) float f32x4;

__device__ inline unsigned short f2h_us(float f) {
  _Float16 h = (_Float16)f;
  return *(unsigned short*)&h;
}

// async global->LDS, 16B per lane, dest = wave-uniform base + lane*16
__device__ inline void gload16(const void* g, void* l) {
  __builtin_amdgcn_global_load_lds((const __attribute__((address_space(1))) unsigned int*)g,
                                   (__attribute__((address_space(3))) unsigned int*)l, 16, 0, 0);
}

// ---------------- merged: degree histogram + weight transposes (one dispatch) ------------

__global__ void k_prepw_degree(const int* __restrict__ dst, int* __restrict__ deg, int E,
                               const float* __restrict__ W0, unsigned short* __restrict__ Wt0,
                               const float* __restrict__ W1, unsigned short* __restrict__ Wt1,
                               const float* __restrict__ W2, unsigned short* __restrict__ Wt2) {
  const int tid = blockIdx.x * blockDim.x + threadIdx.x;
  const int nthr = gridDim.x * blockDim.x;
  for (int e = tid; e < E; e += nthr) atomicAdd(&deg[dst[e]], 1);
  const int S0 = 256 * 256, S1 = 256 * 256, S2 = 128 * 256;
  const int total = S0 + S1 + S2;
  for (int j = tid; j < total; j += nthr) {
    if (j < S0) {
      int nc = j >> 8, k = j & 255;
      Wt0[j] = f2h_us(W0[(size_t)k * 256 + nc]);
    } else if (j < S0 + S1) {
      int t = j - S0;
      int nc = t >> 8, k = t & 255;
      Wt1[t] = f2h_us(W1[(size_t)k * 256 + nc]);
    } else {
      int t = j - S0 - S1;
      int nc = t >> 8, k = t & 255;
      Wt2[t] = (nc < 40) ? f2h_us(W2[(size_t)k * 40 + nc]) : (unsigned short)0;
    }
  }
}

// ---------------- scans ----------------

__global__ void k_scan1(const int* __restrict__ deg, int* __restrict__ rp,
                        int* __restrict__ bsum, int n) {
  __shared__ int sm[256];
  int i = blockIdx.x * 256 + threadIdx.x;
  int v = (i < n) ? deg[i] : 0;
  sm[threadIdx.x] = v;
  __syncthreads();
  for (int off = 1; off < 256; off <<= 1) {
    int t = (threadIdx.x >= off) ? sm[threadIdx.x - off] : 0;
    __syncthreads();
    sm[threadIdx.x] += t;
    __syncthreads();
  }
  if (i < n) rp[i + 1] = sm[threadIdx.x];
  if (threadIdx.x == 255) bsum[blockIdx.x] = sm[255];
}

__global__ void k_scan2(int* bsum, int nb) {
  __shared__ int sm[256];
  int v = (threadIdx.x < nb) ? bsum[threadIdx.x] : 0;
  sm[threadIdx.x] = v;
  __syncthreads();
  for (int off = 1; off < 256; off <<= 1) {
    int t = (threadIdx.x >= off) ? sm[threadIdx.x - off] : 0;
    __syncthreads();
    sm[threadIdx.x] += t;
    __syncthreads();
  }
  if (threadIdx.x < nb) bsum[threadIdx.x] = sm[threadIdx.x] - v;  // exclusive
}

__global__ void k_scan3(int* __restrict__ rp, const int* __restrict__ bsum, int n) {
  int i = blockIdx.x * 256 + threadIdx.x;
  if (i < n) rp[i + 1] += bsum[blockIdx.x];
  if (i == 0) rp[0] = 0;
}

// ---------------- scatter (standalone; R12 split for attribution) ------------------------
// 3.4MB csr written randomly from all 8 XCDs -> cross-XCD line churn (WRITE 57MB),
// ~44us fabric floor. Fused-with-GEMM0 measured sum-like (71us), not max-like.

__global__ void k_scatter(const int* __restrict__ src, const int* __restrict__ dst,
                          const int* __restrict__ rp, int* __restrict__ cur,
                          int* __restrict__ csr, int E) {
  int e = blockIdx.x * blockDim.x + threadIdx.x;
  if (e < E) {
    int d = dst[e];
    int pos = rp[d] + atomicAdd(&cur[d], 1);
    csr[pos] = src[e];
  }
}

// ---------------- full-N GEMM body: 256 threads, 64x256 block, A read ONCE ---------------
// BM=64, 4 waves (1x4), all waves share the A tile. A-f32 XOR swizzle per rule #21
// (R10: conflicts 17.8M->1.2M).

template <bool AF32>
__device__ __forceinline__ void gemmN_body(int bx, const void* Av,
                                           const unsigned short* __restrict__ Bt,
                                           unsigned short* __restrict__ C,
                                           const float* __restrict__ asrc,
                                           const float* __restrict__ adst,
                                           float* __restrict__ a_s, float* __restrict__ a_d,
                                           int M) {
  constexpr int BM = 64, BK = 32, K = 256;
  __shared__ alignas(16) unsigned char AsRaw[BM * BK * (AF32 ? 4 : 2)];  // 8KB / 4KB
  __shared__ alignas(16) unsigned short Bs[256 * BK];                    // 16KB
  int tid = threadIdx.x;
  int wave = tid >> 6, lane = tid & 63;  // 4 waves
  int quad = lane >> 4, l16 = lane & 15;
  int wn = wave * 64;  // 1x4 wave grid; every wave covers all 64 A-rows
  int bm = bx * BM;
  f32x4 acc[4][4] = {};
  const float* Af = (const float*)Av;
  const unsigned short* Ah = (const unsigned short*)Av;
  for (int k0 = 0; k0 < K; k0 += BK) {
#pragma unroll
    for (int it = 0; it < 4; it++) {
      // B unit = 16 rows x 64B (f16): 16 units cover all 256 B-rows
      int u = wave * 4 + it;  // 0..15
      int brow = u * 16 + (lane >> 2);
      int bpart = lane & 3;
      gload16(Bt + (size_t)brow * K + k0 + bpart * 8, Bs + u * 512);
      if (AF32) {
        if (it < 2) {
          // A unit = 8 rows x 128B (f32): 8 units cover 64 rows.
          // Swizzled source slot; linear LDS dest.
          int ua = wave * 2 + it;       // 0..7
          int row = lane >> 3;          // 0..7 within unit
          int part = (lane & 7) ^ row;  // 16B slot, XOR-permuted within the row
          int gm = bm + ua * 8 + row;
          if (gm >= M) gm = M - 1;  // x is an input buffer: clamp, never stray
          gload16(Af + (size_t)gm * K + k0 + part * 4, AsRaw + ua * 1024);
        }
      } else {
        if (it == 0) {
          // A unit = 16 rows x 64B (f16): 4 units cover 64 rows
          int row = wave * 16 + (lane >> 2);
          int part = lane & 3;
          int gm = bm + row;
          if (gm >= M) gm = M - 1;
          gload16(Ah + (size_t)gm * K + k0 + part * 8, AsRaw + wave * 1024);
        }
      }
    }
    __syncthreads();
    half8 af[4], bf[4];
#pragma unroll
    for (int i = 0; i < 4; i++) {
      int arow = i * 16 + l16;  // 0..63
      if (AF32) {
        const float4* As4 = (const float4*)AsRaw;
        int r7 = arow & 7;
        float4 lo = As4[arow * 8 + ((quad * 2) ^ r7)];
        float4 hi = As4[arow * 8 + ((quad * 2 + 1) ^ r7)];
        half8 a;
        a[0] = (_Float16)lo.x; a[1] = (_Float16)lo.y;
        a[2] = (_Float16)lo.z; a[3] = (_Float16)lo.w;
        a[4] = (_Float16)hi.x; a[5] = (_Float16)hi.y;
        a[6] = (_Float16)hi.z; a[7] = (_Float16)hi.w;
        af[i] = a;
      } else {
        af[i] = *(const half8*)((const unsigned short*)AsRaw + arow * BK + quad * 8);
      }
      bf[i] = *(const half8*)(Bs + (wn + i * 16 + l16) * BK + quad * 8);
    }
#pragma unroll
    for (int i = 0; i < 4; i++)
#pragma unroll
      for (int j = 0; j < 4; j++)
        acc[i][j] = __builtin_amdgcn_mfma_f32_16x16x32_f16(af[i], bf[j], acc[i][j], 0, 0, 0);
    __syncthreads();
  }
  // C write (f16, ldc=256)
#pragma unroll
  for (int i = 0; i < 4; i++) {
#pragma unroll
    for (int j = 0; j < 4; j++) {
      int col = wn + j * 16 + l16;
#pragma unroll
      for (int r = 0; r < 4; r++) {
        int row = bm + i * 16 + quad * 4 + r;
        if (row < M) C[(size_t)row * 256 + col] = f2h_us(acc[i][j][r]);
      }
    }
  }
  // fused attention projection epilogue (heads=4; wave == head)
  int ghead = wave;
  float asv[4], adv[4];
#pragma unroll
  for (int j = 0; j < 4; j++) {
    int col = wn + j * 16 + l16;
    asv[j] = asrc[col];
    adv[j] = adst[col];
  }
#pragma unroll
  for (int i = 0; i < 4; i++) {
#pragma unroll
    for (int r = 0; r < 4; r++) {
      float s = acc[i][0][r] * asv[0] + acc[i][1][r] * asv[1] + acc[i][2][r] * asv[2] +
                acc[i][3][r] * asv[3];
      float d = acc[i][0][r] * adv[0] + acc[i][1][r] * adv[1] + acc[i][2][r] * adv[2] +
                acc[i][3][r] * adv[3];
#pragma unroll
      for (int mask = 1; mask <= 8; mask <<= 1) {
        s += __shfl_xor(s, mask, 64);
        d += __shfl_xor(d, mask, 64);
      }
      if (l16 == 0) {
        int row = bm + i * 16 + quad * 4 + r;
        if (row < M) {
          a_s[row * 4 + ghead] = s;
          a_d[row * 4 + ghead] = d;
        }
      }
    }
  }
}

// layer-0 GEMM (f32 A = x, full-N) — standalone for attribution
__global__ __launch_bounds__(256) void k_gemm0(
    const float* __restrict__ A, const unsigned short* __restrict__ Bt,
    unsigned short* __restrict__ C, const float* __restrict__ asrc,
    const float* __restrict__ adst, float* __restrict__ a_s, float* __restrict__ a_d, int M) {
  gemmN_body<true>(blockIdx.x, A, Bt, C, asrc, adst, a_s, a_d, M);
}

// layer-1 GEMM (f16 A, full-N)
__global__ __launch_bounds__(256) void k_gemmN_f16(
    const unsigned short* __restrict__ A, const unsigned short* __restrict__ Bt,
    unsigned short* __restrict__ C, const float* __restrict__ asrc,
    const float* __restrict__ adst, float* __restrict__ a_s, float* __restrict__ a_d, int M) {
  gemmN_body<false>(blockIdx.x, A, Bt, C, asrc, adst, a_s, a_d, M);
}

// ---------------- layer-2 GEMM: original 256-thread 128x128-panel kernel -----------------

__global__ __launch_bounds__(256) void k_mfma_gemm(
    const unsigned short* __restrict__ A, const unsigned short* __restrict__ Bt,
    unsigned short* __restrict__ C, const float* __restrict__ asrc,
    const float* __restrict__ adst, float* __restrict__ a_s, float* __restrict__ a_d, int M,
    int K, int Nc, int ldc, int heads, int acols) {
  constexpr int BM = 128, BK = 32;
  __shared__ unsigned short As[BM * BK];
  __shared__ unsigned short Bs[BM * BK];
  int tid = threadIdx.x;
  int wave = tid >> 6, lane = tid & 63;
  int quad = lane >> 4, l16 = lane & 15;
  int wm = (wave & 1) * 64, wn = (wave >> 1) * 64;
  int bm = blockIdx.x * BM, bn = blockIdx.y * BM;
  int srow = lane >> 2;
  int spart = lane & 3;
  f32x4 acc[4][4] = {};
  for (int k0 = 0; k0 < K; k0 += BK) {
#pragma unroll
    for (int it = 0; it < 2; it++) {
      int chunk = wave * 2 + it;
      int row = chunk * 16 + srow;
      // A stray reads land in adjacent workspace buffers (act16 is followed by
      // weight buffers); all result writes guarded by row < M.
      gload16(A + (size_t)(bm + row) * K + k0 + spart * 8, As + chunk * 512);
      gload16(Bt + (size_t)(bn + row) * K + k0 + spart * 8, Bs + chunk * 512);
    }
    __syncthreads();
    half8 af[4], bf[4];
#pragma unroll
    for (int i = 0; i < 4; i++) {
      af[i] = *(const half8*)(As + (wm + i * 16 + l16) * BK + quad * 8);
      bf[i] = *(const half8*)(Bs + (wn + i * 16 + l16) * BK + quad * 8);
    }
#pragma unroll
    for (int i = 0; i < 4; i++)
#pragma unroll
      for (int j = 0; j < 4; j++)
        acc[i][j] = __builtin_amdgcn_mfma_f32_16x16x32_f16(af[i], bf[j], acc[i][j], 0, 0, 0);
    __syncthreads();
  }
#pragma unroll
  for (int i = 0; i < 4; i++) {
#pragma unroll
    for (int j = 0; j < 4; j++) {
      int col = bn + wn + j * 16 + l16;
      if (col >= Nc) continue;
#pragma unroll
      for (int r = 0; r < 4; r++) {
        int row = bm + wm + i * 16 + quad * 4 + r;
        if (row < M) C[(size_t)row * ldc + col] = f2h_us(acc[i][j][r]);
      }
    }
  }
  int ghead = (bn + wn) >> 6;
  if (ghead < heads) {
    float asv[4], adv[4];
#pragma unroll
    for (int j = 0; j < 4; j++) {
      int col = bn + wn + j * 16 + l16;
      bool ok = col < acols;
      asv[j] = ok ? asrc[col] : 0.f;
      adv[j] = ok ? adst[col] : 0.f;
    }
#pragma unroll
    for (int i = 0; i < 4; i++) {
#pragma unroll
      for (int r = 0; r < 4; r++) {
        float s = acc[i][0][r] * asv[0] + acc[i][1][r] * asv[1] + acc[i][2][r] * asv[2] +
                  acc[i][3][r] * asv[3];
        float d = acc[i][0][r] * adv[0] + acc[i][1][r] * adv[1] + acc[i][2][r] * adv[2] +
                  acc[i][3][r] * adv[3];
#pragma unroll
        for (int mask = 1; mask <= 8; mask <<= 1) {
          s += __shfl_xor(s, mask, 64);
          d += __shfl_xor(d, mask, 64);
        }
        if (l16 == 0) {
          int row = bm + wm + i * 16 + quad * 4 + r;
          if (row < M) {
            a_s[row * heads + ghead] = s;
            a_d[row * heads + ghead] = d;
          }
        }
      }
    }
  }
}

// ---------------- fused softmax+aggregation: wave per node, 256 ch, f16 h ----------------
// R0 structure — FROZEN (locally optimal; survived R1/R2/R5 restructurings).

__global__ __launch_bounds__(256) void k_attn_agg256(
    const int* __restrict__ rp, const int* __restrict__ csr, const _Float16* __restrict__ h,
    const float* __restrict__ a_s, const float* __restrict__ a_d, const float* __restrict__ bias,
    const float* __restrict__ bg, const float* __restrict__ bb, const float* __restrict__ bm,
    const float* __restrict__ bv, unsigned short* __restrict__ out, int n_nodes) {
  int wid = (blockIdx.x * blockDim.x + threadIdx.x) >> 6;
  int lane = threadIdx.x & 63;
  if (wid >= n_nodes) return;
  int n = wid;
  int beg = rp[n], end = rp[n + 1];
  int half = lane >> 5, l32 = lane & 31;
  int head = l32 >> 3;  // 8 lanes x 8 ch per head
  int c = l32 * 8;
  float ad = a_d[n * 4 + head];
  float acc[8] = {};
  float psum = 0.f;
  int e = beg;
  for (; e + 8 <= end; e += 8) {
    int s0 = csr[e + half];
    int s1 = csr[e + 2 + half];
    int s2 = csr[e + 4 + half];
    int s3 = csr[e + 6 + half];
    float x0 = a_s[s0 * 4 + head] + ad;
    float x1 = a_s[s1 * 4 + head] + ad;
    float x2 = a_s[s2 * 4 + head] + ad;
    float x3 = a_s[s3 * 4 + head] + ad;
    half8 v0 = *(const half8*)(h + (size_t)s0 * 256 + c);
    half8 v1 = *(const half8*)(h + (size_t)s1 * 256 + c);
    half8 v2 = *(const half8*)(h + (size_t)s2 * 256 + c);
    half8 v3 = *(const half8*)(h + (size_t)s3 * 256 + c);
    x0 = x0 > 0.f ? x0 : x0 * kSlope;
    x1 = x1 > 0.f ? x1 : x1 * kSlope;
    x2 = x2 > 0.f ? x2 : x2 * kSlope;
    x3 = x3 > 0.f ? x3 : x3 * kSlope;
    float p0 = __expf(x0), p1 = __expf(x1);
    float p2 = __expf(x2), p3 = __expf(x3);
    psum += (p0 + p1) + (p2 + p3);
#pragma unroll
    for (int j = 0; j < 8; j++) {
      acc[j] += (float)v0[j] * p0 + (float)v1[j] * p1;
      acc[j] += (float)v2[j] * p2 + (float)v3[j] * p3;
    }
  }
  for (; e + 2 <= end; e += 2) {
    int s0 = csr[e + half];
    float x0 = a_s[s0 * 4 + head] + ad;
    x0 = x0 > 0.f ? x0 : x0 * kSlope;
    float p0 = __expf(x0);
    psum += p0;
    half8 v0 = *(const half8*)(h + (size_t)s0 * 256 + c);
#pragma unroll
    for (int j = 0; j < 8; j++) acc[j] += (float)v0[j] * p0;
  }
  if (e < end && half == 0) {
    int s0 = csr[e];
    float x0 = a_s[s0 * 4 + head] + ad;
    x0 = x0 > 0.f ? x0 : x0 * kSlope;
    float p0 = __expf(x0);
    psum += p0;
    half8 v0 = *(const half8*)(h + (size_t)s0 * 256 + c);
#pragma unroll
    for (int j = 0; j < 8; j++) acc[j] += (float)v0[j] * p0;
  }
  psum += __shfl_xor(psum, 32, 64);
#pragma unroll
  for (int j = 0; j < 8; j++) acc[j] += __shfl_xor(acc[j], 32, 64);
  if (half == 0) {
    float rden = 1.f / (psum + 1e-16f);
    ushortx8 o;
#pragma unroll
    for (int j = 0; j < 8; j++) {
      float v = acc[j] * rden + bias[c + j];
      v = bg[c + j] * (v - bm[c + j]) * rsqrtf(bv[c + j] + kBnEps) + bb[c + j];
      v = v > 0.f ? v : (__expf(v) - 1.f);  // ELU
      o[j] = f2h_us(v);
    }
    *(ushortx8*)(out + (size_t)n * 256 + c) = o;
  }
}

// ---------------- fused softmax+aggregation: wave per node, 40 ch (packed, stride 40) ----

__global__ __launch_bounds__(256) void k_attn_agg40(
    const int* __restrict__ rp, const int* __restrict__ csr, const _Float16* __restrict__ h,
    const float* __restrict__ a_s, const float* __restrict__ a_d, const float* __restrict__ bias,
    float* __restrict__ out, int n_nodes) {
  int wid = (blockIdx.x * blockDim.x + threadIdx.x) >> 6;
  int lane = threadIdx.x & 63;
  if (wid >= n_nodes) return;
  int n = wid;
  int beg = rp[n], end = rp[n + 1];
  float ad = a_d[n];
  int grp = lane >> 3, l8 = lane & 7;
  int c = l8 * 8;  // valid channels only for l8 < 5
  bool act = l8 < 5;
  float acc[8] = {};
  float psum = 0.f;
  for (int base = beg; base < end; base += 16) {
    int e0 = base + grp;
    int e1 = base + 8 + grp;
    if (e0 < end) {
      int s = csr[e0];
      float x = a_s[s] + ad;
      x = x > 0.f ? x : x * kSlope;
      float p = __expf(x);
      psum += p;
      if (act) {
        half8 hv = *(const half8*)(h + (size_t)s * 40 + c);
#pragma unroll
        for (int j = 0; j < 8; j++) acc[j] += (float)hv[j] * p;
      }
    }
    if (e1 < end) {
      int s = csr[e1];
      float x = a_s[s] + ad;
      x = x > 0.f ? x : x * kSlope;
      float p = __expf(x);
      psum += p;
      if (act) {
        half8 hv = *(const half8*)(h + (size_t)s * 40 + c);
#pragma unroll
        for (int j = 0; j < 8; j++) acc[j] += (float)hv[j] * p;
      }
    }
  }
#pragma unroll
  for (int mask = 8; mask <= 32; mask <<= 1) psum += __shfl_xor(psum, mask, 64);
#pragma unroll
  for (int j = 0; j < 8; j++) {
#pragma unroll
    for (int mask = 8; mask <= 32; mask <<= 1) acc[j] += __shfl_xor(acc[j], mask, 64);
  }
  if (lane < 5) {  // channels 0..39
    float rden = 1.f / (psum + 1e-16f);
    float4 o0, o1;
    o0.x = acc[0] * rden + bias[c + 0];
    o0.y = acc[1] * rden + bias[c + 1];
    o0.z = acc[2] * rden + bias[c + 2];
    o0.w = acc[3] * rden + bias[c + 3];
    o1.x = acc[4] * rden + bias[c + 4];
    o1.y = acc[5] * rden + bias[c + 5];
    o1.z = acc[6] * rden + bias[c + 6];
    o1.w = acc[7] * rden + bias[c + 7];
    *(float4*)(out + (size_t)n * 40 + c) = o0;
    *(float4*)(out + (size_t)n * 40 + c + 4) = o1;
  }
}

// ---------------- driver ----------------

extern "C" void kernel_launch(void* const* d_in, const int* in_sizes, int n_in, void* d_out,
                              int out_size, void* d_ws, size_t ws_size, hipStream_t stream) {
  const float* x = (const float*)d_in[0];
  const int* ei = (const int*)d_in[1];
  const float* W0 = (const float*)d_in[2];
  const float* as0 = (const float*)d_in[3];
  const float* ad0 = (const float*)d_in[4];
  const float* b0 = (const float*)d_in[5];
  const float* bg0 = (const float*)d_in[6];
  const float* bb0 = (const float*)d_in[7];
  const float* bm0 = (const float*)d_in[8];
  const float* bv0 = (const float*)d_in[9];
  const float* W1 = (const float*)d_in[10];
  const float* as1 = (const float*)d_in[11];
  const float* ad1 = (const float*)d_in[12];
  const float* b1 = (const float*)d_in[13];
  const float* bg1 = (const float*)d_in[14];
  const float* bb1 = (const float*)d_in[15];
  const float* bm1 = (const float*)d_in[16];
  const float* bv1 = (const float*)d_in[17];
  const float* W2 = (const float*)d_in[18];
  const float* as2 = (const float*)d_in[19];
  const float* ad2 = (const float*)d_in[20];
  const float* b2 = (const float*)d_in[21];
  float* out = (float*)d_out;

  const int E = in_sizes[1] / 2;
  const int* srcIdx = ei;
  const int* dstIdx = ei + E;

  char* p = (char*)d_ws;
  auto alloc = [&](size_t bytes) -> void* {
    void* r = (void*)p;
    p += (bytes + 255) & ~(size_t)255;
    return r;
  };
  int* rp = (int*)alloc((kN + 1) * sizeof(int));
  int* degcur = (int*)alloc((size_t)2 * kN * sizeof(int));  // deg | cursor
  int* deg = degcur;
  int* cur = degcur + kN;
  int* bsum = (int*)alloc(256 * sizeof(int));
  int* csr = (int*)alloc((size_t)E * sizeof(int));
  float* a_s = (float*)alloc((size_t)kN * 4 * sizeof(float));
  float* a_d = (float*)alloc((size_t)kN * 4 * sizeof(float));
  unsigned short* h16 = (unsigned short*)alloc((size_t)kN * 256 * 2);
  unsigned short* act16 = (unsigned short*)alloc((size_t)kN * 256 * 2);
  unsigned short* Wt0 = (unsigned short*)alloc((size_t)256 * 256 * 2);
  unsigned short* Wt1 = (unsigned short*)alloc((size_t)256 * 256 * 2);
  unsigned short* Wt2 = (unsigned short*)alloc((size_t)128 * 256 * 2);

  const int nb = ceil_div(kN, 256);

  // CSR build; degree hidden under weight transposes
  hipMemsetAsync(degcur, 0, (size_t)2 * kN * sizeof(int), stream);
  k_prepw_degree<<<1024, 256, 0, stream>>>(dstIdx, deg, E, W0, Wt0, W1, Wt1, W2, Wt2);
  k_scan1<<<nb, 256, 0, stream>>>(deg, rp, bsum, kN);
  k_scan2<<<1, 256, 0, stream>>>(bsum, nb);
  k_scan3<<<nb, 256, 0, stream>>>(rp, bsum, kN);
  k_scatter<<<ceil_div(E, 256), 256, 0, stream>>>(srcIdx, dstIdx, rp, cur, csr, E);

  const int gemmBlocks = ceil_div(kN, 64);  // 782 full-N BM=64 blocks
  k_gemm0<<<gemmBlocks, 256, 0, stream>>>(x, Wt0, h16, as0, ad0, a_s, a_d, kN);

  int wpn_blocks = ceil_div(kN, 4);
  dim3 gg2(ceil_div(kN, 128), 1);

  // Layer 0 aggregation
  k_attn_agg256<<<wpn_blocks, 256, 0, stream>>>(rp, csr, (const _Float16*)h16, a_s, a_d, b0, bg0,
                                                bb0, bm0, bv0, act16, kN);

  // Layer 1 (full-N f16 GEMM, BM=64)
  k_gemmN_f16<<<gemmBlocks, 256, 0, stream>>>(act16, Wt1, h16, as1, ad1, a_s, a_d, kN);
  k_attn_agg256<<<wpn_blocks, 256, 0, stream>>>(rp, csr, (const _Float16*)h16, a_s, a_d, b1, bg1,
                                                bb1, bm1, bv1, act16, kN);

  // Layer 2: h2 [N,40] packed (row stride 40) in h16
  k_mfma_gemm<<<gg2, 256, 0, stream>>>(act16, Wt2, h16, as2, ad2, a_s, a_d, kN, 256, 40, 40, 1,
                                       40);
  k_attn_agg40<<<wpn_blocks, 256, 0, stream>>>(rp, csr, (const _Float16*)h16, a_s, a_d, b2, out,
                                               kN);
}

// Round 13
// 428.994 us; speedup vs baseline: 1.0392x; 1.0392x over previous
//
#include <hip/hip_runtime.h>
#include <cstdint>
#include <cstddef>

constexpr int kN = 50000;
constexpr float kSlope = 0.2f;
constexpr float kBnEps = 1e-5f;

static inline int ceil_div(int a, int b) { return (a + b - 1) / b; }

typedef __attribute__((ext_vector_type(8))) _Float16 half8;
typedef __attribute__((ext_vector_type(8))) unsigned short ushortx8;
typedef __attribute__((ext_vector_type(4))) float f32x4;

__device__ inline unsigned short f2h_us(float f) {
  _Float16 h = (_Float16)f;
  return *(unsigned short*)&h;
}

// async global->LDS, 16B per lane, dest = wave-uniform base + lane*16
__device__ inline void gload16(const void* g, void* l) {
  __builtin_amdgcn_global_load_lds((const __attribute__((address_space(1))) unsigned int*)g,
                                   (__attribute__((address_space(3))) unsigned int*)l, 16, 0, 0);
}

// ---------------- merged: degree histogram + weight transposes (one dispatch) ------------

__global__ void k_prepw_degree(const int* __restrict__ dst, int* __restrict__ deg, int E,
                               const float* __restrict__ W0, unsigned short* __restrict__ Wt0,
                               const float* __restrict__ W1, unsigned short* __restrict__ Wt1,
                               const float* __restrict__ W2, unsigned short* __restrict__ Wt2) {
  const int tid = blockIdx.x * blockDim.x + threadIdx.x;
  const int nthr = gridDim.x * blockDim.x;
  for (int e = tid; e < E; e += nthr) atomicAdd(&deg[dst[e]], 1);
  const int S0 = 256 * 256, S1 = 256 * 256, S2 = 128 * 256;
  const int total = S0 + S1 + S2;
  for (int j = tid; j < total; j += nthr) {
    if (j < S0) {
      int nc = j >> 8, k = j & 255;
      Wt0[j] = f2h_us(W0[(size_t)k * 256 + nc]);
    } else if (j < S0 + S1) {
      int t = j - S0;
      int nc = t >> 8, k = t & 255;
      Wt1[t] = f2h_us(W1[(size_t)k * 256 + nc]);
    } else {
      int t = j - S0 - S1;
      int nc = t >> 8, k = t & 255;
      Wt2[t] = (nc < 40) ? f2h_us(W2[(size_t)k * 40 + nc]) : (unsigned short)0;
    }
  }
}

// ---------------- scans ----------------

__global__ void k_scan1(const int* __restrict__ deg, int* __restrict__ rp,
                        int* __restrict__ bsum, int n) {
  __shared__ int sm[256];
  int i = blockIdx.x * 256 + threadIdx.x;
  int v = (i < n) ? deg[i] : 0;
  sm[threadIdx.x] = v;
  __syncthreads();
  for (int off = 1; off < 256; off <<= 1) {
    int t = (threadIdx.x >= off) ? sm[threadIdx.x - off] : 0;
    __syncthreads();
    sm[threadIdx.x] += t;
    __syncthreads();
  }
  if (i < n) rp[i + 1] = sm[threadIdx.x];
  if (threadIdx.x == 255) bsum[blockIdx.x] = sm[255];
}

__global__ void k_scan2(int* bsum, int nb) {
  __shared__ int sm[256];
  int v = (threadIdx.x < nb) ? bsum[threadIdx.x] : 0;
  sm[threadIdx.x] = v;
  __syncthreads();
  for (int off = 1; off < 256; off <<= 1) {
    int t = (threadIdx.x >= off) ? sm[threadIdx.x - off] : 0;
    __syncthreads();
    sm[threadIdx.x] += t;
    __syncthreads();
  }
  if (threadIdx.x < nb) bsum[threadIdx.x] = sm[threadIdx.x] - v;  // exclusive
}

__global__ void k_scan3(int* __restrict__ rp, const int* __restrict__ bsum, int n) {
  int i = blockIdx.x * 256 + threadIdx.x;
  if (i < n) rp[i + 1] += bsum[blockIdx.x];
  if (i == 0) rp[0] = 0;
}

// ---------------- full-N GEMM body: 256 threads, 64x256 block, 2-phase dbuf --------------
// R13: double-buffered LDS + prefetch(t+1)-before-compute(t), ONE barrier per K-step
// (catalog T3-minimum). R12 attribution: gemm0 standalone ~50us vs ~10us content floor
// — the old stage->drain->compute loop ate full load latency every K-step.
// A-f32 XOR swizzle per rule #21 retained (R10: conflicts 17.8M->1.2M).

template <bool AF32>
__device__ __forceinline__ void gemmN_body(int bx, const void* Av,
                                           const unsigned short* __restrict__ Bt,
                                           unsigned short* __restrict__ C,
                                           const float* __restrict__ asrc,
                                           const float* __restrict__ adst,
                                           float* __restrict__ a_s, float* __restrict__ a_d,
                                           int M) {
  constexpr int BM = 64, BK = 32, K = 256, NT = K / BK;
  __shared__ alignas(16) unsigned char AsRaw[2][BM * BK * (AF32 ? 4 : 2)];  // 2x8KB / 2x4KB
  __shared__ alignas(16) unsigned short Bs[2][256 * BK];                    // 2x16KB
  int tid = threadIdx.x;
  int wave = tid >> 6, lane = tid & 63;  // 4 waves
  int quad = lane >> 4, l16 = lane & 15;
  int wn = wave * 64;  // 1x4 wave grid; every wave covers all 64 A-rows
  int bm = bx * BM;
  f32x4 acc[4][4] = {};
  const float* Af = (const float*)Av;
  const unsigned short* Ah = (const unsigned short*)Av;

  auto stage = [&](int b, int k0) {
#pragma unroll
    for (int it = 0; it < 4; it++) {
      // B unit = 16 rows x 64B (f16): 16 units cover all 256 B-rows
      int u = wave * 4 + it;  // 0..15
      int brow = u * 16 + (lane >> 2);
      int bpart = lane & 3;
      gload16(Bt + (size_t)brow * K + k0 + bpart * 8, &Bs[b][u * 512]);
      if (AF32) {
        if (it < 2) {
          // A unit = 8 rows x 128B (f32): 8 units cover 64 rows.
          // Swizzled source slot; linear LDS dest.
          int ua = wave * 2 + it;       // 0..7
          int row = lane >> 3;          // 0..7 within unit
          int part = (lane & 7) ^ row;  // 16B slot, XOR-permuted within the row
          int gm = bm + ua * 8 + row;
          if (gm >= M) gm = M - 1;  // x is an input buffer: clamp, never stray
          gload16(Af + (size_t)gm * K + k0 + part * 4, &AsRaw[b][ua * 1024]);
        }
      } else {
        if (it == 0) {
          // A unit = 16 rows x 64B (f16): 4 units cover 64 rows
          int row = wave * 16 + (lane >> 2);
          int part = lane & 3;
          int gm = bm + row;
          if (gm >= M) gm = M - 1;
          gload16(Ah + (size_t)gm * K + k0 + part * 8, &AsRaw[b][wave * 1024]);
        }
      }
    }
  };

  stage(0, 0);
  __syncthreads();  // drain prologue loads (vmcnt0) + all waves ready
  int cur = 0;
  for (int t = 0; t < NT; ++t) {
    if (t + 1 < NT) stage(cur ^ 1, (t + 1) * BK);  // prefetch flies during compute
    half8 af[4], bf[4];
#pragma unroll
    for (int i = 0; i < 4; i++) {
      int arow = i * 16 + l16;  // 0..63
      if (AF32) {
        const float4* As4 = (const float4*)&AsRaw[cur][0];
        int r7 = arow & 7;
        float4 lo = As4[arow * 8 + ((quad * 2) ^ r7)];
        float4 hi = As4[arow * 8 + ((quad * 2 + 1) ^ r7)];
        half8 a;
        a[0] = (_Float16)lo.x; a[1] = (_Float16)lo.y;
        a[2] = (_Float16)lo.z; a[3] = (_Float16)lo.w;
        a[4] = (_Float16)hi.x; a[5] = (_Float16)hi.y;
        a[6] = (_Float16)hi.z; a[7] = (_Float16)hi.w;
        af[i] = a;
      } else {
        af[i] = *(const half8*)((const unsigned short*)&AsRaw[cur][0] + arow * BK + quad * 8);
      }
      bf[i] = *(const half8*)(&Bs[cur][(wn + i * 16 + l16) * BK + quad * 8]);
    }
#pragma unroll
    for (int i = 0; i < 4; i++)
#pragma unroll
      for (int j = 0; j < 4; j++)
        acc[i][j] = __builtin_amdgcn_mfma_f32_16x16x32_f16(af[i], bf[j], acc[i][j], 0, 0, 0);
    __syncthreads();  // drains prefetch (vmcnt0 happens AFTER compute) + buffer-swap safety
    cur ^= 1;
  }
  // C write (f16, ldc=256)
#pragma unroll
  for (int i = 0; i < 4; i++) {
#pragma unroll
    for (int j = 0; j < 4; j++) {
      int col = wn + j * 16 + l16;
#pragma unroll
      for (int r = 0; r < 4; r++) {
        int row = bm + i * 16 + quad * 4 + r;
        if (row < M) C[(size_t)row * 256 + col] = f2h_us(acc[i][j][r]);
      }
    }
  }
  // fused attention projection epilogue (heads=4; wave == head)
  int ghead = wave;
  float asv[4], adv[4];
#pragma unroll
  for (int j = 0; j < 4; j++) {
    int col = wn + j * 16 + l16;
    asv[j] = asrc[col];
    adv[j] = adst[col];
  }
#pragma unroll
  for (int i = 0; i < 4; i++) {
#pragma unroll
    for (int r = 0; r < 4; r++) {
      float s = acc[i][0][r] * asv[0] + acc[i][1][r] * asv[1] + acc[i][2][r] * asv[2] +
                acc[i][3][r] * asv[3];
      float d = acc[i][0][r] * adv[0] + acc[i][1][r] * adv[1] + acc[i][2][r] * adv[2] +
                acc[i][3][r] * adv[3];
#pragma unroll
      for (int mask = 1; mask <= 8; mask <<= 1) {
        s += __shfl_xor(s, mask, 64);
        d += __shfl_xor(d, mask, 64);
      }
      if (l16 == 0) {
        int row = bm + i * 16 + quad * 4 + r;
        if (row < M) {
          a_s[row * 4 + ghead] = s;
          a_d[row * 4 + ghead] = d;
        }
      }
    }
  }
}

// layer-0 GEMM (f32 A = x, full-N) + CSR scatter fused (R11 config: fusion is max-like,
// scatter's 44us hides under the GEMM — R12 split cost +23us)
__global__ __launch_bounds__(256) void k_gemm0_scatter(
    const float* __restrict__ A, const unsigned short* __restrict__ Bt,
    unsigned short* __restrict__ C, const float* __restrict__ asrc,
    const float* __restrict__ adst, float* __restrict__ a_s, float* __restrict__ a_d, int M,
    int gemmBlocks, const int* __restrict__ src, const int* __restrict__ dst,
    const int* __restrict__ rp, int* __restrict__ cur, int* __restrict__ csr, int E) {
  if ((int)blockIdx.x < gemmBlocks) {
    gemmN_body<true>(blockIdx.x, A, Bt, C, asrc, adst, a_s, a_d, M);
  } else {
    int e = (blockIdx.x - gemmBlocks) * 256 + threadIdx.x;
    if (e < E) {
      int d = dst[e];
      int pos = rp[d] + atomicAdd(&cur[d], 1);
      csr[pos] = src[e];
    }
  }
}

// layer-1 GEMM (f16 A, full-N)
__global__ __launch_bounds__(256) void k_gemmN_f16(
    const unsigned short* __restrict__ A, const unsigned short* __restrict__ Bt,
    unsigned short* __restrict__ C, const float* __restrict__ asrc,
    const float* __restrict__ adst, float* __restrict__ a_s, float* __restrict__ a_d, int M) {
  gemmN_body<false>(blockIdx.x, A, Bt, C, asrc, adst, a_s, a_d, M);
}

// ---------------- layer-2 GEMM: original 256-thread 128x128-panel kernel -----------------

__global__ __launch_bounds__(256) void k_mfma_gemm(
    const unsigned short* __restrict__ A, const unsigned short* __restrict__ Bt,
    unsigned short* __restrict__ C, const float* __restrict__ asrc,
    const float* __restrict__ adst, float* __restrict__ a_s, float* __restrict__ a_d, int M,
    int K, int Nc, int ldc, int heads, int acols) {
  constexpr int BM = 128, BK = 32;
  __shared__ unsigned short As[BM * BK];
  __shared__ unsigned short Bs[BM * BK];
  int tid = threadIdx.x;
  int wave = tid >> 6, lane = tid & 63;
  int quad = lane >> 4, l16 = lane & 15;
  int wm = (wave & 1) * 64, wn = (wave >> 1) * 64;
  int bm = blockIdx.x * BM, bn = blockIdx.y * BM;
  int srow = lane >> 2;
  int spart = lane & 3;
  f32x4 acc[4][4] = {};
  for (int k0 = 0; k0 < K; k0 += BK) {
#pragma unroll
    for (int it = 0; it < 2; it++) {
      int chunk = wave * 2 + it;
      int row = chunk * 16 + srow;
      // A stray reads land in adjacent workspace buffers (act16 is followed by
      // weight buffers); all result writes guarded by row < M.
      gload16(A + (size_t)(bm + row) * K + k0 + spart * 8, As + chunk * 512);
      gload16(Bt + (size_t)(bn + row) * K + k0 + spart * 8, Bs + chunk * 512);
    }
    __syncthreads();
    half8 af[4], bf[4];
#pragma unroll
    for (int i = 0; i < 4; i++) {
      af[i] = *(const half8*)(As + (wm + i * 16 + l16) * BK + quad * 8);
      bf[i] = *(const half8*)(Bs + (wn + i * 16 + l16) * BK + quad * 8);
    }
#pragma unroll
    for (int i = 0; i < 4; i++)
#pragma unroll
      for (int j = 0; j < 4; j++)
        acc[i][j] = __builtin_amdgcn_mfma_f32_16x16x32_f16(af[i], bf[j], acc[i][j], 0, 0, 0);
    __syncthreads();
  }
#pragma unroll
  for (int i = 0; i < 4; i++) {
#pragma unroll
    for (int j = 0; j < 4; j++) {
      int col = bn + wn + j * 16 + l16;
      if (col >= Nc) continue;
#pragma unroll
      for (int r = 0; r < 4; r++) {
        int row = bm + wm + i * 16 + quad * 4 + r;
        if (row < M) C[(size_t)row * ldc + col] = f2h_us(acc[i][j][r]);
      }
    }
  }
  int ghead = (bn + wn) >> 6;
  if (ghead < heads) {
    float asv[4], adv[4];
#pragma unroll
    for (int j = 0; j < 4; j++) {
      int col = bn + wn + j * 16 + l16;
      bool ok = col < acols;
      asv[j] = ok ? asrc[col] : 0.f;
      adv[j] = ok ? adst[col] : 0.f;
    }
#pragma unroll
    for (int i = 0; i < 4; i++) {
#pragma unroll
      for (int r = 0; r < 4; r++) {
        float s = acc[i][0][r] * asv[0] + acc[i][1][r] * asv[1] + acc[i][2][r] * asv[2] +
                  acc[i][3][r] * asv[3];
        float d = acc[i][0][r] * adv[0] + acc[i][1][r] * adv[1] + acc[i][2][r] * adv[2] +
                  acc[i][3][r] * adv[3];
#pragma unroll
        for (int mask = 1; mask <= 8; mask <<= 1) {
          s += __shfl_xor(s, mask, 64);
          d += __shfl_xor(d, mask, 64);
        }
        if (l16 == 0) {
          int row = bm + wm + i * 16 + quad * 4 + r;
          if (row < M) {
            a_s[row * heads + ghead] = s;
            a_d[row * heads + ghead] = d;
          }
        }
      }
    }
  }
}

// ---------------- fused softmax+aggregation: wave per node, 256 ch, f16 h ----------------
// R0 structure — FROZEN (locally optimal; survived R1/R2/R5 restructurings).

__global__ __launch_bounds__(256) void k_attn_agg256(
    const int* __restrict__ rp, const int* __restrict__ csr, const _Float16* __restrict__ h,
    const float* __restrict__ a_s, const float* __restrict__ a_d, const float* __restrict__ bias,
    const float* __restrict__ bg, const float* __restrict__ bb, const float* __restrict__ bm,
    const float* __restrict__ bv, unsigned short* __restrict__ out, int n_nodes) {
  int wid = (blockIdx.x * blockDim.x + threadIdx.x) >> 6;
  int lane = threadIdx.x & 63;
  if (wid >= n_nodes) return;
  int n = wid;
  int beg = rp[n], end = rp[n + 1];
  int half = lane >> 5, l32 = lane & 31;
  int head = l32 >> 3;  // 8 lanes x 8 ch per head
  int c = l32 * 8;
  float ad = a_d[n * 4 + head];
  float acc[8] = {};
  float psum = 0.f;
  int e = beg;
  for (; e + 8 <= end; e += 8) {
    int s0 = csr[e + half];
    int s1 = csr[e + 2 + half];
    int s2 = csr[e + 4 + half];
    int s3 = csr[e + 6 + half];
    float x0 = a_s[s0 * 4 + head] + ad;
    float x1 = a_s[s1 * 4 + head] + ad;
    float x2 = a_s[s2 * 4 + head] + ad;
    float x3 = a_s[s3 * 4 + head] + ad;
    half8 v0 = *(const half8*)(h + (size_t)s0 * 256 + c);
    half8 v1 = *(const half8*)(h + (size_t)s1 * 256 + c);
    half8 v2 = *(const half8*)(h + (size_t)s2 * 256 + c);
    half8 v3 = *(const half8*)(h + (size_t)s3 * 256 + c);
    x0 = x0 > 0.f ? x0 : x0 * kSlope;
    x1 = x1 > 0.f ? x1 : x1 * kSlope;
    x2 = x2 > 0.f ? x2 : x2 * kSlope;
    x3 = x3 > 0.f ? x3 : x3 * kSlope;
    float p0 = __expf(x0), p1 = __expf(x1);
    float p2 = __expf(x2), p3 = __expf(x3);
    psum += (p0 + p1) + (p2 + p3);
#pragma unroll
    for (int j = 0; j < 8; j++) {
      acc[j] += (float)v0[j] * p0 + (float)v1[j] * p1;
      acc[j] += (float)v2[j] * p2 + (float)v3[j] * p3;
    }
  }
  for (; e + 2 <= end; e += 2) {
    int s0 = csr[e + half];
    float x0 = a_s[s0 * 4 + head] + ad;
    x0 = x0 > 0.f ? x0 : x0 * kSlope;
    float p0 = __expf(x0);
    psum += p0;
    half8 v0 = *(const half8*)(h + (size_t)s0 * 256 + c);
#pragma unroll
    for (int j = 0; j < 8; j++) acc[j] += (float)v0[j] * p0;
  }
  if (e < end && half == 0) {
    int s0 = csr[e];
    float x0 = a_s[s0 * 4 + head] + ad;
    x0 = x0 > 0.f ? x0 : x0 * kSlope;
    float p0 = __expf(x0);
    psum += p0;
    half8 v0 = *(const half8*)(h + (size_t)s0 * 256 + c);
#pragma unroll
    for (int j = 0; j < 8; j++) acc[j] += (float)v0[j] * p0;
  }
  psum += __shfl_xor(psum, 32, 64);
#pragma unroll
  for (int j = 0; j < 8; j++) acc[j] += __shfl_xor(acc[j], 32, 64);
  if (half == 0) {
    float rden = 1.f / (psum + 1e-16f);
    ushortx8 o;
#pragma unroll
    for (int j = 0; j < 8; j++) {
      float v = acc[j] * rden + bias[c + j];
      v = bg[c + j] * (v - bm[c + j]) * rsqrtf(bv[c + j] + kBnEps) + bb[c + j];
      v = v > 0.f ? v : (__expf(v) - 1.f);  // ELU
      o[j] = f2h_us(v);
    }
    *(ushortx8*)(out + (size_t)n * 256 + c) = o;
  }
}

// ---------------- fused softmax+aggregation: wave per node, 40 ch (packed, stride 40) ----

__global__ __launch_bounds__(256) void k_attn_agg40(
    const int* __restrict__ rp, const int* __restrict__ csr, const _Float16* __restrict__ h,
    const float* __restrict__ a_s, const float* __restrict__ a_d, const float* __restrict__ bias,
    float* __restrict__ out, int n_nodes) {
  int wid = (blockIdx.x * blockDim.x + threadIdx.x) >> 6;
  int lane = threadIdx.x & 63;
  if (wid >= n_nodes) return;
  int n = wid;
  int beg = rp[n], end = rp[n + 1];
  float ad = a_d[n];
  int grp = lane >> 3, l8 = lane & 7;
  int c = l8 * 8;  // valid channels only for l8 < 5
  bool act = l8 < 5;
  float acc[8] = {};
  float psum = 0.f;
  for (int base = beg; base < end; base += 16) {
    int e0 = base + grp;
    int e1 = base + 8 + grp;
    if (e0 < end) {
      int s = csr[e0];
      float x = a_s[s] + ad;
      x = x > 0.f ? x : x * kSlope;
      float p = __expf(x);
      psum += p;
      if (act) {
        half8 hv = *(const half8*)(h + (size_t)s * 40 + c);
#pragma unroll
        for (int j = 0; j < 8; j++) acc[j] += (float)hv[j] * p;
      }
    }
    if (e1 < end) {
      int s = csr[e1];
      float x = a_s[s] + ad;
      x = x > 0.f ? x : x * kSlope;
      float p = __expf(x);
      psum += p;
      if (act) {
        half8 hv = *(const half8*)(h + (size_t)s * 40 + c);
#pragma unroll
        for (int j = 0; j < 8; j++) acc[j] += (float)hv[j] * p;
      }
    }
  }
#pragma unroll
  for (int mask = 8; mask <= 32; mask <<= 1) psum += __shfl_xor(psum, mask, 64);
#pragma unroll
  for (int j = 0; j < 8; j++) {
#pragma unroll
    for (int mask = 8; mask <= 32; mask <<= 1) acc[j] += __shfl_xor(acc[j], mask, 64);
  }
  if (lane < 5) {  // channels 0..39
    float rden = 1.f / (psum + 1e-16f);
    float4 o0, o1;
    o0.x = acc[0] * rden + bias[c + 0];
    o0.y = acc[1] * rden + bias[c + 1];
    o0.z = acc[2] * rden + bias[c + 2];
    o0.w = acc[3] * rden + bias[c + 3];
    o1.x = acc[4] * rden + bias[c + 4];
    o1.y = acc[5] * rden + bias[c + 5];
    o1.z = acc[6] * rden + bias[c + 6];
    o1.w = acc[7] * rden + bias[c + 7];
    *(float4*)(out + (size_t)n * 40 + c) = o0;
    *(float4*)(out + (size_t)n * 40 + c + 4) = o1;
  }
}

// ---------------- driver ----------------

extern "C" void kernel_launch(void* const* d_in, const int* in_sizes, int n_in, void* d_out,
                              int out_size, void* d_ws, size_t ws_size, hipStream_t stream) {
  const float* x = (const float*)d_in[0];
  const int* ei = (const int*)d_in[1];
  const float* W0 = (const float*)d_in[2];
  const float* as0 = (const float*)d_in[3];
  const float* ad0 = (const float*)d_in[4];
  const float* b0 = (const float*)d_in[5];
  const float* bg0 = (const float*)d_in[6];
  const float* bb0 = (const float*)d_in[7];
  const float* bm0 = (const float*)d_in[8];
  const float* bv0 = (const float*)d_in[9];
  const float* W1 = (const float*)d_in[10];
  const float* as1 = (const float*)d_in[11];
  const float* ad1 = (const float*)d_in[12];
  const float* b1 = (const float*)d_in[13];
  const float* bg1 = (const float*)d_in[14];
  const float* bb1 = (const float*)d_in[15];
  const float* bm1 = (const float*)d_in[16];
  const float* bv1 = (const float*)d_in[17];
  const float* W2 = (const float*)d_in[18];
  const float* as2 = (const float*)d_in[19];
  const float* ad2 = (const float*)d_in[20];
  const float* b2 = (const float*)d_in[21];
  float* out = (float*)d_out;

  const int E = in_sizes[1] / 2;
  const int* srcIdx = ei;
  const int* dstIdx = ei + E;

  char* p = (char*)d_ws;
  auto alloc = [&](size_t bytes) -> void* {
    void* r = (void*)p;
    p += (bytes + 255) & ~(size_t)255;
    return r;
  };
  int* rp = (int*)alloc((kN + 1) * sizeof(int));
  int* degcur = (int*)alloc((size_t)2 * kN * sizeof(int));  // deg | cursor
  int* deg = degcur;
  int* cur = degcur + kN;
  int* bsum = (int*)alloc(256 * sizeof(int));
  int* csr = (int*)alloc((size_t)E * sizeof(int));
  float* a_s = (float*)alloc((size_t)kN * 4 * sizeof(float));
  float* a_d = (float*)alloc((size_t)kN * 4 * sizeof(float));
  unsigned short* h16 = (unsigned short*)alloc((size_t)kN * 256 * 2);
  unsigned short* act16 = (unsigned short*)alloc((size_t)kN * 256 * 2);
  unsigned short* Wt0 = (unsigned short*)alloc((size_t)256 * 256 * 2);
  unsigned short* Wt1 = (unsigned short*)alloc((size_t)256 * 256 * 2);
  unsigned short* Wt2 = (unsigned short*)alloc((size_t)128 * 256 * 2);

  const int nb = ceil_div(kN, 256);

  // CSR build overlapped with prep/GEMM0:
  hipMemsetAsync(degcur, 0, (size_t)2 * kN * sizeof(int), stream);
  k_prepw_degree<<<1024, 256, 0, stream>>>(dstIdx, deg, E, W0, Wt0, W1, Wt1, W2, Wt2);
  k_scan1<<<nb, 256, 0, stream>>>(deg, rp, bsum, kN);
  k_scan2<<<1, 256, 0, stream>>>(bsum, nb);
  k_scan3<<<nb, 256, 0, stream>>>(rp, bsum, kN);

  const int gemmBlocks = ceil_div(kN, 64);  // 782 full-N BM=64 blocks
  const int sblocks = ceil_div(E, 256);
  k_gemm0_scatter<<<gemmBlocks + sblocks, 256, 0, stream>>>(
      x, Wt0, h16, as0, ad0, a_s, a_d, kN, gemmBlocks, srcIdx, dstIdx, rp, cur, csr, E);

  int wpn_blocks = ceil_div(kN, 4);
  dim3 gg2(ceil_div(kN, 128), 1);

  // Layer 0 aggregation
  k_attn_agg256<<<wpn_blocks, 256, 0, stream>>>(rp, csr, (const _Float16*)h16, a_s, a_d, b0, bg0,
                                                bb0, bm0, bv0, act16, kN);

  // Layer 1 (full-N f16 GEMM, BM=64, 2-phase dbuf)
  k_gemmN_f16<<<gemmBlocks, 256, 0, stream>>>(act16, Wt1, h16, as1, ad1, a_s, a_d, kN);
  k_attn_agg256<<<wpn_blocks, 256, 0, stream>>>(rp, csr, (const _Float16*)h16, a_s, a_d, b1, bg1,
                                                bb1, bm1, bv1, act16, kN);

  // Layer 2: h2 [N,40] packed (row stride 40) in h16
  k_mfma_gemm<<<gg2, 256, 0, stream>>>(act16, Wt2, h16, as2, ad2, a_s, a_d, kN, 256, 40, 40, 1,
                                       40);
  k_attn_agg40<<<wpn_blocks, 256, 0, stream>>>(rp, csr, (const _Float16*)h16, a_s, a_d, b2, out,
                                               kN);
}

// Round 14
// 418.939 us; speedup vs baseline: 1.0641x; 1.0240x over previous
//
#include <hip/hip_runtime.h>
#include <cstdint>
#include <cstddef>

constexpr int kN = 50000;
constexpr float kSlope = 0.2f;
constexpr float kBnEps = 1e-5f;

static inline int ceil_div(int a, int b) { return (a + b - 1) / b; }

typedef __attribute__((ext_vector_type(8))) _Float16 half8;
typedef __attribute__((ext_vector_type(8))) unsigned short ushortx8;
typedef __attribute__((ext_vector_type(4))) float f32x4;

__device__ inline unsigned short f2h_us(float f) {
  _Float16 h = (_Float16)f;
  return *(unsigned short*)&h;
}

// async global->LDS, 16B per lane, dest = wave-uniform base + lane*16
__device__ inline void gload16(const void* g, void* l) {
  __builtin_amdgcn_global_load_lds((const __attribute__((address_space(1))) unsigned int*)g,
                                   (__attribute__((address_space(3))) unsigned int*)l, 16, 0, 0);
}

// ---------------- merged: degree histogram + weight transposes (one dispatch) ------------

__global__ void k_prepw_degree(const int* __restrict__ dst, int* __restrict__ deg, int E,
                               const float* __restrict__ W0, unsigned short* __restrict__ Wt0,
                               const float* __restrict__ W1, unsigned short* __restrict__ Wt1,
                               const float* __restrict__ W2, unsigned short* __restrict__ Wt2) {
  const int tid = blockIdx.x * blockDim.x + threadIdx.x;
  const int nthr = gridDim.x * blockDim.x;
  for (int e = tid; e < E; e += nthr) atomicAdd(&deg[dst[e]], 1);
  const int S0 = 256 * 256, S1 = 256 * 256, S2 = 128 * 256;
  const int total = S0 + S1 + S2;
  for (int j = tid; j < total; j += nthr) {
    if (j < S0) {
      int nc = j >> 8, k = j & 255;
      Wt0[j] = f2h_us(W0[(size_t)k * 256 + nc]);
    } else if (j < S0 + S1) {
      int t = j - S0;
      int nc = t >> 8, k = t & 255;
      Wt1[t] = f2h_us(W1[(size_t)k * 256 + nc]);
    } else {
      int t = j - S0 - S1;
      int nc = t >> 8, k = t & 255;
      Wt2[t] = (nc < 40) ? f2h_us(W2[(size_t)k * 40 + nc]) : (unsigned short)0;
    }
  }
}

// ---------------- scans ----------------

__global__ void k_scan1(const int* __restrict__ deg, int* __restrict__ rp,
                        int* __restrict__ bsum, int n) {
  __shared__ int sm[256];
  int i = blockIdx.x * 256 + threadIdx.x;
  int v = (i < n) ? deg[i] : 0;
  sm[threadIdx.x] = v;
  __syncthreads();
  for (int off = 1; off < 256; off <<= 1) {
    int t = (threadIdx.x >= off) ? sm[threadIdx.x - off] : 0;
    __syncthreads();
    sm[threadIdx.x] += t;
    __syncthreads();
  }
  if (i < n) rp[i + 1] = sm[threadIdx.x];
  if (threadIdx.x == 255) bsum[blockIdx.x] = sm[255];
}

__global__ void k_scan2(int* bsum, int nb) {
  __shared__ int sm[256];
  int v = (threadIdx.x < nb) ? bsum[threadIdx.x] : 0;
  sm[threadIdx.x] = v;
  __syncthreads();
  for (int off = 1; off < 256; off <<= 1) {
    int t = (threadIdx.x >= off) ? sm[threadIdx.x - off] : 0;
    __syncthreads();
    sm[threadIdx.x] += t;
    __syncthreads();
  }
  if (threadIdx.x < nb) bsum[threadIdx.x] = sm[threadIdx.x] - v;  // exclusive
}

__global__ void k_scan3(int* __restrict__ rp, const int* __restrict__ bsum, int n) {
  int i = blockIdx.x * 256 + threadIdx.x;
  if (i < n) rp[i + 1] += bsum[blockIdx.x];
  if (i == 0) rp[0] = 0;
}

// ---------------- full-N GEMM body: 256 threads, 64x256 block, BK=64 ---------------------
// R14: BK 32->64, SINGLE buffer. dbuf was null (R13, matches guide m99/m100): the lever
// is the NUMBER of stage->drain->compute epochs, not overlap. 4 epochs instead of 8.
// All LDS fragment reads XOR-swizzled per rule #21 (128/256B row strides would otherwise
// be 16-way conflicts): linear gload_lds dest + inverse-swizzled GLOBAL slot + same XOR
// on the read. Lanes sharing a slot differ only in row -> 2 lanes/bank = free (m136).
// LDS: 48KB (f32-A) / 40KB (f16-A) -> 3-4 blocks/CU, all 782 blocks co-resident.

template <bool AF32>
__device__ __forceinline__ void gemmN_body(int bx, const void* Av,
                                           const unsigned short* __restrict__ Bt,
                                           unsigned short* __restrict__ C,
                                           const float* __restrict__ asrc,
                                           const float* __restrict__ adst,
                                           float* __restrict__ a_s, float* __restrict__ a_d,
                                           int M) {
  constexpr int BM = 64, BK = 64, K = 256, NT = K / BK;
  __shared__ alignas(16) unsigned char AsRaw[BM * BK * (AF32 ? 4 : 2)];  // 16KB / 8KB
  __shared__ alignas(16) unsigned short Bs[256 * BK];                    // 32KB
  int tid = threadIdx.x;
  int wave = tid >> 6, lane = tid & 63;  // 4 waves
  int quad = lane >> 4, l16 = lane & 15;
  int wn = wave * 64;  // 1x4 wave grid; every wave covers all 64 A-rows
  int bm = bx * BM;
  f32x4 acc[4][4] = {};
  const float* Af = (const float*)Av;
  const unsigned short* Ah = (const unsigned short*)Av;

  for (int t = 0; t < NT; ++t) {
    int k0 = t * BK;
#pragma unroll
    for (int it = 0; it < 8; it++) {
      // B unit = 8 rows x 128B: 32 units cover all 256 B-rows
      int u = wave * 8 + it;  // 0..31
      int brow = u * 8 + (lane >> 3);
      int bslot = (lane & 7) ^ (brow & 7);  // inverse-swizzled source slot (16B)
      gload16(Bt + (size_t)brow * K + k0 + bslot * 8, (unsigned char*)Bs + u * 1024);
      if (AF32) {
        if (it < 4) {
          // A unit = 4 rows x 256B (f32): 16 units cover 64 rows
          int ua = wave * 4 + it;  // 0..15
          int row = ua * 4 + (lane >> 4);
          int aslot = (lane & 15) ^ (row & 15);  // 16 slots of 16B per 256B row
          int gm = bm + row;
          if (gm >= M) gm = M - 1;  // x is an input buffer: clamp, never stray
          gload16(Af + (size_t)gm * K + k0 + aslot * 4, AsRaw + ua * 1024);
        }
      } else {
        if (it < 2) {
          // A unit = 8 rows x 128B (f16): 8 units cover 64 rows
          int ua = wave * 2 + it;  // 0..7
          int row = ua * 8 + (lane >> 3);
          int aslot = (lane & 7) ^ (row & 7);
          int gm = bm + row;
          if (gm >= M) gm = M - 1;
          gload16(Ah + (size_t)gm * K + k0 + aslot * 8, AsRaw + ua * 1024);
        }
      }
    }
    __syncthreads();  // drain loads; all waves see full tile
#pragma unroll
    for (int kk = 0; kk < 2; ++kk) {  // two K=32 sub-steps per staged BK=64 tile
      half8 af[4], bf[4];
#pragma unroll
      for (int i = 0; i < 4; i++) {
        int arow = i * 16 + l16;  // 0..63
        if (AF32) {
          const float4* As4 = (const float4*)AsRaw;
          int r15 = arow & 15;
          int sl = kk * 8 + quad * 2;  // logical 16B slot of the 8-float fragment
          float4 lo = As4[arow * 16 + (sl ^ r15)];
          float4 hi = As4[arow * 16 + ((sl + 1) ^ r15)];
          half8 a;
          a[0] = (_Float16)lo.x; a[1] = (_Float16)lo.y;
          a[2] = (_Float16)lo.z; a[3] = (_Float16)lo.w;
          a[4] = (_Float16)hi.x; a[5] = (_Float16)hi.y;
          a[6] = (_Float16)hi.z; a[7] = (_Float16)hi.w;
          af[i] = a;
        } else {
          int phys = (kk * 4 + quad) ^ (arow & 7);  // 16B slot within 128B row
          af[i] = *(const half8*)((const unsigned short*)AsRaw + arow * 64 + phys * 8);
        }
        int brow = wn + i * 16 + l16;
        int bphys = (kk * 4 + quad) ^ (brow & 7);
        bf[i] = *(const half8*)(Bs + (size_t)brow * 64 + bphys * 8);
      }
#pragma unroll
      for (int i = 0; i < 4; i++)
#pragma unroll
        for (int j = 0; j < 4; j++)
          acc[i][j] = __builtin_amdgcn_mfma_f32_16x16x32_f16(af[i], bf[j], acc[i][j], 0, 0, 0);
    }
    __syncthreads();  // tile consumed; safe to restage
  }
  // C write (f16, ldc=256)
#pragma unroll
  for (int i = 0; i < 4; i++) {
#pragma unroll
    for (int j = 0; j < 4; j++) {
      int col = wn + j * 16 + l16;
#pragma unroll
      for (int r = 0; r < 4; r++) {
        int row = bm + i * 16 + quad * 4 + r;
        if (row < M) C[(size_t)row * 256 + col] = f2h_us(acc[i][j][r]);
      }
    }
  }
  // fused attention projection epilogue (heads=4; wave == head)
  int ghead = wave;
  float asv[4], adv[4];
#pragma unroll
  for (int j = 0; j < 4; j++) {
    int col = wn + j * 16 + l16;
    asv[j] = asrc[col];
    adv[j] = adst[col];
  }
#pragma unroll
  for (int i = 0; i < 4; i++) {
#pragma unroll
    for (int r = 0; r < 4; r++) {
      float s = acc[i][0][r] * asv[0] + acc[i][1][r] * asv[1] + acc[i][2][r] * asv[2] +
                acc[i][3][r] * asv[3];
      float d = acc[i][0][r] * adv[0] + acc[i][1][r] * adv[1] + acc[i][2][r] * adv[2] +
                acc[i][3][r] * adv[3];
#pragma unroll
      for (int mask = 1; mask <= 8; mask <<= 1) {
        s += __shfl_xor(s, mask, 64);
        d += __shfl_xor(d, mask, 64);
      }
      if (l16 == 0) {
        int row = bm + i * 16 + quad * 4 + r;
        if (row < M) {
          a_s[row * 4 + ghead] = s;
          a_d[row * 4 + ghead] = d;
        }
      }
    }
  }
}

// layer-0 GEMM (f32 A = x, full-N) + CSR scatter fused (R11: fusion is max-like;
// scatter's 44us hides under the GEMM — R12 split cost +23us)
__global__ __launch_bounds__(256) void k_gemm0_scatter(
    const float* __restrict__ A, const unsigned short* __restrict__ Bt,
    unsigned short* __restrict__ C, const float* __restrict__ asrc,
    const float* __restrict__ adst, float* __restrict__ a_s, float* __restrict__ a_d, int M,
    int gemmBlocks, const int* __restrict__ src, const int* __restrict__ dst,
    const int* __restrict__ rp, int* __restrict__ cur, int* __restrict__ csr, int E) {
  if ((int)blockIdx.x < gemmBlocks) {
    gemmN_body<true>(blockIdx.x, A, Bt, C, asrc, adst, a_s, a_d, M);
  } else {
    int e = (blockIdx.x - gemmBlocks) * 256 + threadIdx.x;
    if (e < E) {
      int d = dst[e];
      int pos = rp[d] + atomicAdd(&cur[d], 1);
      csr[pos] = src[e];
    }
  }
}

// layer-1 GEMM (f16 A, full-N)
__global__ __launch_bounds__(256) void k_gemmN_f16(
    const unsigned short* __restrict__ A, const unsigned short* __restrict__ Bt,
    unsigned short* __restrict__ C, const float* __restrict__ asrc,
    const float* __restrict__ adst, float* __restrict__ a_s, float* __restrict__ a_d, int M) {
  gemmN_body<false>(blockIdx.x, A, Bt, C, asrc, adst, a_s, a_d, M);
}

// ---------------- layer-2 GEMM: original 256-thread 128x128-panel kernel -----------------

__global__ __launch_bounds__(256) void k_mfma_gemm(
    const unsigned short* __restrict__ A, const unsigned short* __restrict__ Bt,
    unsigned short* __restrict__ C, const float* __restrict__ asrc,
    const float* __restrict__ adst, float* __restrict__ a_s, float* __restrict__ a_d, int M,
    int K, int Nc, int ldc, int heads, int acols) {
  constexpr int BM = 128, BK = 32;
  __shared__ unsigned short As[BM * BK];
  __shared__ unsigned short Bs[BM * BK];
  int tid = threadIdx.x;
  int wave = tid >> 6, lane = tid & 63;
  int quad = lane >> 4, l16 = lane & 15;
  int wm = (wave & 1) * 64, wn = (wave >> 1) * 64;
  int bm = blockIdx.x * BM, bn = blockIdx.y * BM;
  int srow = lane >> 2;
  int spart = lane & 3;
  f32x4 acc[4][4] = {};
  for (int k0 = 0; k0 < K; k0 += BK) {
#pragma unroll
    for (int it = 0; it < 2; it++) {
      int chunk = wave * 2 + it;
      int row = chunk * 16 + srow;
      // A stray reads land in adjacent workspace buffers (act16 is followed by
      // weight buffers); all result writes guarded by row < M.
      gload16(A + (size_t)(bm + row) * K + k0 + spart * 8, As + chunk * 512);
      gload16(Bt + (size_t)(bn + row) * K + k0 + spart * 8, Bs + chunk * 512);
    }
    __syncthreads();
    half8 af[4], bf[4];
#pragma unroll
    for (int i = 0; i < 4; i++) {
      af[i] = *(const half8*)(As + (wm + i * 16 + l16) * BK + quad * 8);
      bf[i] = *(const half8*)(Bs + (wn + i * 16 + l16) * BK + quad * 8);
    }
#pragma unroll
    for (int i = 0; i < 4; i++)
#pragma unroll
      for (int j = 0; j < 4; j++)
        acc[i][j] = __builtin_amdgcn_mfma_f32_16x16x32_f16(af[i], bf[j], acc[i][j], 0, 0, 0);
    __syncthreads();
  }
#pragma unroll
  for (int i = 0; i < 4; i++) {
#pragma unroll
    for (int j = 0; j < 4; j++) {
      int col = bn + wn + j * 16 + l16;
      if (col >= Nc) continue;
#pragma unroll
      for (int r = 0; r < 4; r++) {
        int row = bm + wm + i * 16 + quad * 4 + r;
        if (row < M) C[(size_t)row * ldc + col] = f2h_us(acc[i][j][r]);
      }
    }
  }
  int ghead = (bn + wn) >> 6;
  if (ghead < heads) {
    float asv[4], adv[4];
#pragma unroll
    for (int j = 0; j < 4; j++) {
      int col = bn + wn + j * 16 + l16;
      bool ok = col < acols;
      asv[j] = ok ? asrc[col] : 0.f;
      adv[j] = ok ? adst[col] : 0.f;
    }
#pragma unroll
    for (int i = 0; i < 4; i++) {
#pragma unroll
      for (int r = 0; r < 4; r++) {
        float s = acc[i][0][r] * asv[0] + acc[i][1][r] * asv[1] + acc[i][2][r] * asv[2] +
                  acc[i][3][r] * asv[3];
        float d = acc[i][0][r] * adv[0] + acc[i][1][r] * adv[1] + acc[i][2][r] * adv[2] +
                  acc[i][3][r] * adv[3];
#pragma unroll
        for (int mask = 1; mask <= 8; mask <<= 1) {
          s += __shfl_xor(s, mask, 64);
          d += __shfl_xor(d, mask, 64);
        }
        if (l16 == 0) {
          int row = bm + wm + i * 16 + quad * 4 + r;
          if (row < M) {
            a_s[row * heads + ghead] = s;
            a_d[row * heads + ghead] = d;
          }
        }
      }
    }
  }
}

// ---------------- fused softmax+aggregation: wave per node, 256 ch, f16 h ----------------
// R0 structure — FROZEN (locally optimal; survived R1/R2/R5 restructurings).

__global__ __launch_bounds__(256) void k_attn_agg256(
    const int* __restrict__ rp, const int* __restrict__ csr, const _Float16* __restrict__ h,
    const float* __restrict__ a_s, const float* __restrict__ a_d, const float* __restrict__ bias,
    const float* __restrict__ bg, const float* __restrict__ bb, const float* __restrict__ bm,
    const float* __restrict__ bv, unsigned short* __restrict__ out, int n_nodes) {
  int wid = (blockIdx.x * blockDim.x + threadIdx.x) >> 6;
  int lane = threadIdx.x & 63;
  if (wid >= n_nodes) return;
  int n = wid;
  int beg = rp[n], end = rp[n + 1];
  int half = lane >> 5, l32 = lane & 31;
  int head = l32 >> 3;  // 8 lanes x 8 ch per head
  int c = l32 * 8;
  float ad = a_d[n * 4 + head];
  float acc[8] = {};
  float psum = 0.f;
  int e = beg;
  for (; e + 8 <= end; e += 8) {
    int s0 = csr[e + half];
    int s1 = csr[e + 2 + half];
    int s2 = csr[e + 4 + half];
    int s3 = csr[e + 6 + half];
    float x0 = a_s[s0 * 4 + head] + ad;
    float x1 = a_s[s1 * 4 + head] + ad;
    float x2 = a_s[s2 * 4 + head] + ad;
    float x3 = a_s[s3 * 4 + head] + ad;
    half8 v0 = *(const half8*)(h + (size_t)s0 * 256 + c);
    half8 v1 = *(const half8*)(h + (size_t)s1 * 256 + c);
    half8 v2 = *(const half8*)(h + (size_t)s2 * 256 + c);
    half8 v3 = *(const half8*)(h + (size_t)s3 * 256 + c);
    x0 = x0 > 0.f ? x0 : x0 * kSlope;
    x1 = x1 > 0.f ? x1 : x1 * kSlope;
    x2 = x2 > 0.f ? x2 : x2 * kSlope;
    x3 = x3 > 0.f ? x3 : x3 * kSlope;
    float p0 = __expf(x0), p1 = __expf(x1);
    float p2 = __expf(x2), p3 = __expf(x3);
    psum += (p0 + p1) + (p2 + p3);
#pragma unroll
    for (int j = 0; j < 8; j++) {
      acc[j] += (float)v0[j] * p0 + (float)v1[j] * p1;
      acc[j] += (float)v2[j] * p2 + (float)v3[j] * p3;
    }
  }
  for (; e + 2 <= end; e += 2) {
    int s0 = csr[e + half];
    float x0 = a_s[s0 * 4 + head] + ad;
    x0 = x0 > 0.f ? x0 : x0 * kSlope;
    float p0 = __expf(x0);
    psum += p0;
    half8 v0 = *(const half8*)(h + (size_t)s0 * 256 + c);
#pragma unroll
    for (int j = 0; j < 8; j++) acc[j] += (float)v0[j] * p0;
  }
  if (e < end && half == 0) {
    int s0 = csr[e];
    float x0 = a_s[s0 * 4 + head] + ad;
    x0 = x0 > 0.f ? x0 : x0 * kSlope;
    float p0 = __expf(x0);
    psum += p0;
    half8 v0 = *(const half8*)(h + (size_t)s0 * 256 + c);
#pragma unroll
    for (int j = 0; j < 8; j++) acc[j] += (float)v0[j] * p0;
  }
  psum += __shfl_xor(psum, 32, 64);
#pragma unroll
  for (int j = 0; j < 8; j++) acc[j] += __shfl_xor(acc[j], 32, 64);
  if (half == 0) {
    float rden = 1.f / (psum + 1e-16f);
    ushortx8 o;
#pragma unroll
    for (int j = 0; j < 8; j++) {
      float v = acc[j] * rden + bias[c + j];
      v = bg[c + j] * (v - bm[c + j]) * rsqrtf(bv[c + j] + kBnEps) + bb[c + j];
      v = v > 0.f ? v : (__expf(v) - 1.f);  // ELU
      o[j] = f2h_us(v);
    }
    *(ushortx8*)(out + (size_t)n * 256 + c) = o;
  }
}

// ---------------- fused softmax+aggregation: wave per node, 40 ch (packed, stride 40) ----

__global__ __launch_bounds__(256) void k_attn_agg40(
    const int* __restrict__ rp, const int* __restrict__ csr, const _Float16* __restrict__ h,
    const float* __restrict__ a_s, const float* __restrict__ a_d, const float* __restrict__ bias,
    float* __restrict__ out, int n_nodes) {
  int wid = (blockIdx.x * blockDim.x + threadIdx.x) >> 6;
  int lane = threadIdx.x & 63;
  if (wid >= n_nodes) return;
  int n = wid;
  int beg = rp[n], end = rp[n + 1];
  float ad = a_d[n];
  int grp = lane >> 3, l8 = lane & 7;
  int c = l8 * 8;  // valid channels only for l8 < 5
  bool act = l8 < 5;
  float acc[8] = {};
  float psum = 0.f;
  for (int base = beg; base < end; base += 16) {
    int e0 = base + grp;
    int e1 = base + 8 + grp;
    if (e0 < end) {
      int s = csr[e0];
      float x = a_s[s] + ad;
      x = x > 0.f ? x : x * kSlope;
      float p = __expf(x);
      psum += p;
      if (act) {
        half8 hv = *(const half8*)(h + (size_t)s * 40 + c);
#pragma unroll
        for (int j = 0; j < 8; j++) acc[j] += (float)hv[j] * p;
      }
    }
    if (e1 < end) {
      int s = csr[e1];
      float x = a_s[s] + ad;
      x = x > 0.f ? x : x * kSlope;
      float p = __expf(x);
      psum += p;
      if (act) {
        half8 hv = *(const half8*)(h + (size_t)s * 40 + c);
#pragma unroll
        for (int j = 0; j < 8; j++) acc[j] += (float)hv[j] * p;
      }
    }
  }
#pragma unroll
  for (int mask = 8; mask <= 32; mask <<= 1) psum += __shfl_xor(psum, mask, 64);
#pragma unroll
  for (int j = 0; j < 8; j++) {
#pragma unroll
    for (int mask = 8; mask <= 32; mask <<= 1) acc[j] += __shfl_xor(acc[j], mask, 64);
  }
  if (lane < 5) {  // channels 0..39
    float rden = 1.f / (psum + 1e-16f);
    float4 o0, o1;
    o0.x = acc[0] * rden + bias[c + 0];
    o0.y = acc[1] * rden + bias[c + 1];
    o0.z = acc[2] * rden + bias[c + 2];
    o0.w = acc[3] * rden + bias[c + 3];
    o1.x = acc[4] * rden + bias[c + 4];
    o1.y = acc[5] * rden + bias[c + 5];
    o1.z = acc[6] * rden + bias[c + 6];
    o1.w = acc[7] * rden + bias[c + 7];
    *(float4*)(out + (size_t)n * 40 + c) = o0;
    *(float4*)(out + (size_t)n * 40 + c + 4) = o1;
  }
}

// ---------------- driver ----------------

extern "C" void kernel_launch(void* const* d_in, const int* in_sizes, int n_in, void* d_out,
                              int out_size, void* d_ws, size_t ws_size, hipStream_t stream) {
  const float* x = (const float*)d_in[0];
  const int* ei = (const int*)d_in[1];
  const float* W0 = (const float*)d_in[2];
  const float* as0 = (const float*)d_in[3];
  const float* ad0 = (const float*)d_in[4];
  const float* b0 = (const float*)d_in[5];
  const float* bg0 = (const float*)d_in[6];
  const float* bb0 = (const float*)d_in[7];
  const float* bm0 = (const float*)d_in[8];
  const float* bv0 = (const float*)d_in[9];
  const float* W1 = (const float*)d_in[10];
  const float* as1 = (const float*)d_in[11];
  const float* ad1 = (const float*)d_in[12];
  const float* b1 = (const float*)d_in[13];
  const float* bg1 = (const float*)d_in[14];
  const float* bb1 = (const float*)d_in[15];
  const float* bm1 = (const float*)d_in[16];
  const float* bv1 = (const float*)d_in[17];
  const float* W2 = (const float*)d_in[18];
  const float* as2 = (const float*)d_in[19];
  const float* ad2 = (const float*)d_in[20];
  const float* b2 = (const float*)d_in[21];
  float* out = (float*)d_out;

  const int E = in_sizes[1] / 2;
  const int* srcIdx = ei;
  const int* dstIdx = ei + E;

  char* p = (char*)d_ws;
  auto alloc = [&](size_t bytes) -> void* {
    void* r = (void*)p;
    p += (bytes + 255) & ~(size_t)255;
    return r;
  };
  int* rp = (int*)alloc((kN + 1) * sizeof(int));
  int* degcur = (int*)alloc((size_t)2 * kN * sizeof(int));  // deg | cursor
  int* deg = degcur;
  int* cur = degcur + kN;
  int* bsum = (int*)alloc(256 * sizeof(int));
  int* csr = (int*)alloc((size_t)E * sizeof(int));
  float* a_s = (float*)alloc((size_t)kN * 4 * sizeof(float));
  float* a_d = (float*)alloc((size_t)kN * 4 * sizeof(float));
  unsigned short* h16 = (unsigned short*)alloc((size_t)kN * 256 * 2);
  unsigned short* act16 = (unsigned short*)alloc((size_t)kN * 256 * 2);
  unsigned short* Wt0 = (unsigned short*)alloc((size_t)256 * 256 * 2);
  unsigned short* Wt1 = (unsigned short*)alloc((size_t)256 * 256 * 2);
  unsigned short* Wt2 = (unsigned short*)alloc((size_t)128 * 256 * 2);

  const int nb = ceil_div(kN, 256);

  // CSR build overlapped with prep/GEMM0:
  hipMemsetAsync(degcur, 0, (size_t)2 * kN * sizeof(int), stream);
  k_prepw_degree<<<1024, 256, 0, stream>>>(dstIdx, deg, E, W0, Wt0, W1, Wt1, W2, Wt2);
  k_scan1<<<nb, 256, 0, stream>>>(deg, rp, bsum, kN);
  k_scan2<<<1, 256, 0, stream>>>(bsum, nb);
  k_scan3<<<nb, 256, 0, stream>>>(rp, bsum, kN);

  const int gemmBlocks = ceil_div(kN, 64);  // 782 full-N BM=64 blocks
  const int sblocks = ceil_div(E, 256);
  k_gemm0_scatter<<<gemmBlocks + sblocks, 256, 0, stream>>>(
      x, Wt0, h16, as0, ad0, a_s, a_d, kN, gemmBlocks, srcIdx, dstIdx, rp, cur, csr, E);

  int wpn_blocks = ceil_div(kN, 4);
  dim3 gg2(ceil_div(kN, 128), 1);

  // Layer 0 aggregation
  k_attn_agg256<<<wpn_blocks, 256, 0, stream>>>(rp, csr, (const _Float16*)h16, a_s, a_d, b0, bg0,
                                                bb0, bm0, bv0, act16, kN);

  // Layer 1 (full-N f16 GEMM, BM=64, BK=64)
  k_gemmN_f16<<<gemmBlocks, 256, 0, stream>>>(act16, Wt1, h16, as1, ad1, a_s, a_d, kN);
  k_attn_agg256<<<wpn_blocks, 256, 0, stream>>>(rp, csr, (const _Float16*)h16, a_s, a_d, b1, bg1,
                                                bb1, bm1, bv1, act16, kN);

  // Layer 2: h2 [N,40] packed (row stride 40) in h16
  k_mfma_gemm<<<gg2, 256, 0, stream>>>(act16, Wt2, h16, as2, ad2, a_s, a_d, kN, 256, 40, 40, 1,
                                       40);
  k_attn_agg40<<<wpn_blocks, 256, 0, stream>>>(rp, csr, (const _Float16*)h16, a_s, a_d, b2, out,
                                               kN);
}

// Round 15
// 407.936 us; speedup vs baseline: 1.0928x; 1.0270x over previous
//
#include <hip/hip_runtime.h>
#include <cstdint>
#include <cstddef>

constexpr int kN = 50000;
constexpr float kSlope = 0.2f;
constexpr float kBnEps = 1e-5f;

static inline int ceil_div(int a, int b) { return (a + b - 1) / b; }

typedef __attribute__((ext_vector_type(8))) _Float16 half8;
typedef __attribute__((ext_vector_type(8))) unsigned short ushortx8;
typedef __attribute__((ext_vector_type(4))) float f32x4;

__device__ inline unsigned short f2h_us(float f) {
  _Float16 h = (_Float16)f;
  return *(unsigned short*)&h;
}

// async global->LDS, 16B per lane, dest = wave-uniform base + lane*16
__device__ inline void gload16(const void* g, void* l) {
  __builtin_amdgcn_global_load_lds((const __attribute__((address_space(1))) unsigned int*)g,
                                   (__attribute__((address_space(3))) unsigned int*)l, 16, 0, 0);
}

// ---------------- merged: degree histogram + weight transposes (one dispatch) ------------

__global__ void k_prepw_degree(const int* __restrict__ dst, int* __restrict__ deg, int E,
                               const float* __restrict__ W0, unsigned short* __restrict__ Wt0,
                               const float* __restrict__ W1, unsigned short* __restrict__ Wt1,
                               const float* __restrict__ W2, unsigned short* __restrict__ Wt2) {
  const int tid = blockIdx.x * blockDim.x + threadIdx.x;
  const int nthr = gridDim.x * blockDim.x;
  for (int e = tid; e < E; e += nthr) atomicAdd(&deg[dst[e]], 1);
  const int S0 = 256 * 256, S1 = 256 * 256, S2 = 128 * 256;
  const int total = S0 + S1 + S2;
  for (int j = tid; j < total; j += nthr) {
    if (j < S0) {
      int nc = j >> 8, k = j & 255;
      Wt0[j] = f2h_us(W0[(size_t)k * 256 + nc]);
    } else if (j < S0 + S1) {
      int t = j - S0;
      int nc = t >> 8, k = t & 255;
      Wt1[t] = f2h_us(W1[(size_t)k * 256 + nc]);
    } else {
      int t = j - S0 - S1;
      int nc = t >> 8, k = t & 255;
      Wt2[t] = (nc < 40) ? f2h_us(W2[(size_t)k * 40 + nc]) : (unsigned short)0;
    }
  }
}

// ---------------- scans ----------------

__global__ void k_scan1(const int* __restrict__ deg, int* __restrict__ rp,
                        int* __restrict__ bsum, int n) {
  __shared__ int sm[256];
  int i = blockIdx.x * 256 + threadIdx.x;
  int v = (i < n) ? deg[i] : 0;
  sm[threadIdx.x] = v;
  __syncthreads();
  for (int off = 1; off < 256; off <<= 1) {
    int t = (threadIdx.x >= off) ? sm[threadIdx.x - off] : 0;
    __syncthreads();
    sm[threadIdx.x] += t;
    __syncthreads();
  }
  if (i < n) rp[i + 1] = sm[threadIdx.x];
  if (threadIdx.x == 255) bsum[blockIdx.x] = sm[255];
}

__global__ void k_scan2(int* bsum, int nb) {
  __shared__ int sm[256];
  int v = (threadIdx.x < nb) ? bsum[threadIdx.x] : 0;
  sm[threadIdx.x] = v;
  __syncthreads();
  for (int off = 1; off < 256; off <<= 1) {
    int t = (threadIdx.x >= off) ? sm[threadIdx.x - off] : 0;
    __syncthreads();
    sm[threadIdx.x] += t;
    __syncthreads();
  }
  if (threadIdx.x < nb) bsum[threadIdx.x] = sm[threadIdx.x] - v;  // exclusive
}

__global__ void k_scan3(int* __restrict__ rp, const int* __restrict__ bsum, int n) {
  int i = blockIdx.x * 256 + threadIdx.x;
  if (i < n) rp[i + 1] += bsum[blockIdx.x];
  if (i == 0) rp[0] = 0;
}

// ---------------- full-N GEMM body: 256 threads, 64x256 block, BK=64 ---------------------
// R14 structure (proven): single buffer, 4 stage->drain->compute epochs, rule-#21
// XOR swizzle on all LDS fragment paths.

template <bool AF32>
__device__ __forceinline__ void gemmN_body(int bx, const void* Av,
                                           const unsigned short* __restrict__ Bt,
                                           unsigned short* __restrict__ C,
                                           const float* __restrict__ asrc,
                                           const float* __restrict__ adst,
                                           float* __restrict__ a_s, float* __restrict__ a_d,
                                           int M) {
  constexpr int BM = 64, BK = 64, K = 256, NT = K / BK;
  __shared__ alignas(16) unsigned char AsRaw[BM * BK * (AF32 ? 4 : 2)];  // 16KB / 8KB
  __shared__ alignas(16) unsigned short Bs[256 * BK];                    // 32KB
  int tid = threadIdx.x;
  int wave = tid >> 6, lane = tid & 63;  // 4 waves
  int quad = lane >> 4, l16 = lane & 15;
  int wn = wave * 64;  // 1x4 wave grid; every wave covers all 64 A-rows
  int bm = bx * BM;
  f32x4 acc[4][4] = {};
  const float* Af = (const float*)Av;
  const unsigned short* Ah = (const unsigned short*)Av;

  for (int t = 0; t < NT; ++t) {
    int k0 = t * BK;
#pragma unroll
    for (int it = 0; it < 8; it++) {
      // B unit = 8 rows x 128B: 32 units cover all 256 B-rows
      int u = wave * 8 + it;  // 0..31
      int brow = u * 8 + (lane >> 3);
      int bslot = (lane & 7) ^ (brow & 7);  // inverse-swizzled source slot (16B)
      gload16(Bt + (size_t)brow * K + k0 + bslot * 8, (unsigned char*)Bs + u * 1024);
      if (AF32) {
        if (it < 4) {
          // A unit = 4 rows x 256B (f32): 16 units cover 64 rows
          int ua = wave * 4 + it;  // 0..15
          int row = ua * 4 + (lane >> 4);
          int aslot = (lane & 15) ^ (row & 15);  // 16 slots of 16B per 256B row
          int gm = bm + row;
          if (gm >= M) gm = M - 1;  // x is an input buffer: clamp, never stray
          gload16(Af + (size_t)gm * K + k0 + aslot * 4, AsRaw + ua * 1024);
        }
      } else {
        if (it < 2) {
          // A unit = 8 rows x 128B (f16): 8 units cover 64 rows
          int ua = wave * 2 + it;  // 0..7
          int row = ua * 8 + (lane >> 3);
          int aslot = (lane & 7) ^ (row & 7);
          int gm = bm + row;
          if (gm >= M) gm = M - 1;
          gload16(Ah + (size_t)gm * K + k0 + aslot * 8, AsRaw + ua * 1024);
        }
      }
    }
    __syncthreads();  // drain loads; all waves see full tile
#pragma unroll
    for (int kk = 0; kk < 2; ++kk) {  // two K=32 sub-steps per staged BK=64 tile
      half8 af[4], bf[4];
#pragma unroll
      for (int i = 0; i < 4; i++) {
        int arow = i * 16 + l16;  // 0..63
        if (AF32) {
          const float4* As4 = (const float4*)AsRaw;
          int r15 = arow & 15;
          int sl = kk * 8 + quad * 2;  // logical 16B slot of the 8-float fragment
          float4 lo = As4[arow * 16 + (sl ^ r15)];
          float4 hi = As4[arow * 16 + ((sl + 1) ^ r15)];
          half8 a;
          a[0] = (_Float16)lo.x; a[1] = (_Float16)lo.y;
          a[2] = (_Float16)lo.z; a[3] = (_Float16)lo.w;
          a[4] = (_Float16)hi.x; a[5] = (_Float16)hi.y;
          a[6] = (_Float16)hi.z; a[7] = (_Float16)hi.w;
          af[i] = a;
        } else {
          int phys = (kk * 4 + quad) ^ (arow & 7);  // 16B slot within 128B row
          af[i] = *(const half8*)((const unsigned short*)AsRaw + arow * 64 + phys * 8);
        }
        int brow = wn + i * 16 + l16;
        int bphys = (kk * 4 + quad) ^ (brow & 7);
        bf[i] = *(const half8*)(Bs + (size_t)brow * 64 + bphys * 8);
      }
#pragma unroll
      for (int i = 0; i < 4; i++)
#pragma unroll
        for (int j = 0; j < 4; j++)
          acc[i][j] = __builtin_amdgcn_mfma_f32_16x16x32_f16(af[i], bf[j], acc[i][j], 0, 0, 0);
    }
    __syncthreads();  // tile consumed; safe to restage
  }
  // C write (f16, ldc=256)
#pragma unroll
  for (int i = 0; i < 4; i++) {
#pragma unroll
    for (int j = 0; j < 4; j++) {
      int col = wn + j * 16 + l16;
#pragma unroll
      for (int r = 0; r < 4; r++) {
        int row = bm + i * 16 + quad * 4 + r;
        if (row < M) C[(size_t)row * 256 + col] = f2h_us(acc[i][j][r]);
      }
    }
  }
  // fused attention projection epilogue (heads=4; wave == head)
  int ghead = wave;
  float asv[4], adv[4];
#pragma unroll
  for (int j = 0; j < 4; j++) {
    int col = wn + j * 16 + l16;
    asv[j] = asrc[col];
    adv[j] = adst[col];
  }
#pragma unroll
  for (int i = 0; i < 4; i++) {
#pragma unroll
    for (int r = 0; r < 4; r++) {
      float s = acc[i][0][r] * asv[0] + acc[i][1][r] * asv[1] + acc[i][2][r] * asv[2] +
                acc[i][3][r] * asv[3];
      float d = acc[i][0][r] * adv[0] + acc[i][1][r] * adv[1] + acc[i][2][r] * adv[2] +
                acc[i][3][r] * adv[3];
#pragma unroll
      for (int mask = 1; mask <= 8; mask <<= 1) {
        s += __shfl_xor(s, mask, 64);
        d += __shfl_xor(d, mask, 64);
      }
      if (l16 == 0) {
        int row = bm + i * 16 + quad * 4 + r;
        if (row < M) {
          a_s[row * 4 + ghead] = s;
          a_d[row * 4 + ghead] = d;
        }
      }
    }
  }
}

// layer-0 GEMM (f32 A = x, full-N) + CSR scatter fused (R11: fusion is max-like;
// scatter's 44us hides under the GEMM — R12 split cost +23us)
__global__ __launch_bounds__(256) void k_gemm0_scatter(
    const float* __restrict__ A, const unsigned short* __restrict__ Bt,
    unsigned short* __restrict__ C, const float* __restrict__ asrc,
    const float* __restrict__ adst, float* __restrict__ a_s, float* __restrict__ a_d, int M,
    int gemmBlocks, const int* __restrict__ src, const int* __restrict__ dst,
    const int* __restrict__ rp, int* __restrict__ cur, int* __restrict__ csr, int E) {
  if ((int)blockIdx.x < gemmBlocks) {
    gemmN_body<true>(blockIdx.x, A, Bt, C, asrc, adst, a_s, a_d, M);
  } else {
    int e = (blockIdx.x - gemmBlocks) * 256 + threadIdx.x;
    if (e < E) {
      int d = dst[e];
      int pos = rp[d] + atomicAdd(&cur[d], 1);
      csr[pos] = src[e];
    }
  }
}

// layer-1 GEMM (f16 A, full-N)
__global__ __launch_bounds__(256) void k_gemmN_f16(
    const unsigned short* __restrict__ A, const unsigned short* __restrict__ Bt,
    unsigned short* __restrict__ C, const float* __restrict__ asrc,
    const float* __restrict__ adst, float* __restrict__ a_s, float* __restrict__ a_d, int M) {
  gemmN_body<false>(blockIdx.x, A, Bt, C, asrc, adst, a_s, a_d, M);
}

// ---------------- layer-2 GEMM: dedicated 40-col kernel (R15) ----------------------------
// Old k_mfma_gemm computed a 128-col MFMA tile with only 40 live cols (69% dead work,
// 391 blocks, 8 epochs). k_gemm40: BM=64 (782 blocks), BK=64 (4 epochs, R14 structure),
// 3 N-tiles = 48 cols (Wt2 rows 40..47 are zero-padded). Per-wave acc[3]; wave w owns
// rows [w*16, w*16+16). Fused heads=1 projection epilogue. A/B staged with linear
// gload_lds dest + rule-#21 XOR slot swizzle (same recipe as gemmN_body f16 path).

__global__ __launch_bounds__(256) void k_gemm40(
    const unsigned short* __restrict__ A, const unsigned short* __restrict__ Bt,
    unsigned short* __restrict__ C, const float* __restrict__ asrc,
    const float* __restrict__ adst, float* __restrict__ a_s, float* __restrict__ a_d, int M) {
  constexpr int BM = 64, BK = 64, K = 256, NT = K / BK;
  __shared__ alignas(16) unsigned short As[BM * BK];  // 8KB
  __shared__ alignas(16) unsigned short Bs[48 * BK];  // 6KB
  int tid = threadIdx.x;
  int wave = tid >> 6, lane = tid & 63;  // 4 waves
  int quad = lane >> 4, l16 = lane & 15;
  int bm = blockIdx.x * BM;
  f32x4 acc[3] = {};
  for (int t = 0; t < NT; ++t) {
    int k0 = t * BK;
#pragma unroll
    for (int it = 0; it < 2; it++) {
      // A unit = 8 rows x 128B: 8 units cover 64 rows
      int ua = wave * 2 + it;  // 0..7
      int arow = ua * 8 + (lane >> 3);
      int aslot = (lane & 7) ^ (arow & 7);
      int gm = bm + arow;
      if (gm >= M) gm = M - 1;  // act16 clamp
      gload16(A + (size_t)gm * K + k0 + aslot * 8, (unsigned char*)As + ua * 1024);
      // B unit = 8 rows x 128B: 6 units cover 48 rows (waves 0..2 only)
      int ub = wave * 2 + it;
      if (ub < 6) {
        int brow = ub * 8 + (lane >> 3);
        int bslot = (lane & 7) ^ (brow & 7);
        gload16(Bt + (size_t)brow * K + k0 + bslot * 8, (unsigned char*)Bs + ub * 1024);
      }
    }
    __syncthreads();
#pragma unroll
    for (int kk = 0; kk < 2; ++kk) {
      int arow = wave * 16 + l16;
      int aphys = (kk * 4 + quad) ^ (arow & 7);
      half8 af = *(const half8*)(As + (size_t)arow * 64 + aphys * 8);
#pragma unroll
      for (int j = 0; j < 3; j++) {
        int brow = j * 16 + l16;
        int bphys = (kk * 4 + quad) ^ (brow & 7);
        half8 bf = *(const half8*)(Bs + (size_t)brow * 64 + bphys * 8);
        acc[j] = __builtin_amdgcn_mfma_f32_16x16x32_f16(af, bf, acc[j], 0, 0, 0);
      }
    }
    __syncthreads();
  }
  // C write (f16, packed ldc=40) + fused heads=1 projection
  float asv[3], adv[3];
#pragma unroll
  for (int j = 0; j < 3; j++) {
    int col = j * 16 + l16;
    bool ok = col < 40;
    asv[j] = ok ? asrc[col] : 0.f;
    adv[j] = ok ? adst[col] : 0.f;
  }
#pragma unroll
  for (int r = 0; r < 4; r++) {
    int row = bm + wave * 16 + quad * 4 + r;
    bool rok = row < M;
#pragma unroll
    for (int j = 0; j < 3; j++) {
      int col = j * 16 + l16;
      if (rok && col < 40) C[(size_t)row * 40 + col] = f2h_us(acc[j][r]);
    }
    float s = acc[0][r] * asv[0] + acc[1][r] * asv[1] + acc[2][r] * asv[2];
    float d = acc[0][r] * adv[0] + acc[1][r] * adv[1] + acc[2][r] * adv[2];
#pragma unroll
    for (int mask = 1; mask <= 8; mask <<= 1) {
      s += __shfl_xor(s, mask, 64);
      d += __shfl_xor(d, mask, 64);
    }
    if (l16 == 0 && rok) {
      a_s[row] = s;
      a_d[row] = d;
    }
  }
}

// ---------------- fused softmax+aggregation: wave per node, 256 ch, f16 h ----------------
// R0 structure — FROZEN (locally optimal; survived R1/R2/R5 restructurings).

__global__ __launch_bounds__(256) void k_attn_agg256(
    const int* __restrict__ rp, const int* __restrict__ csr, const _Float16* __restrict__ h,
    const float* __restrict__ a_s, const float* __restrict__ a_d, const float* __restrict__ bias,
    const float* __restrict__ bg, const float* __restrict__ bb, const float* __restrict__ bm,
    const float* __restrict__ bv, unsigned short* __restrict__ out, int n_nodes) {
  int wid = (blockIdx.x * blockDim.x + threadIdx.x) >> 6;
  int lane = threadIdx.x & 63;
  if (wid >= n_nodes) return;
  int n = wid;
  int beg = rp[n], end = rp[n + 1];
  int half = lane >> 5, l32 = lane & 31;
  int head = l32 >> 3;  // 8 lanes x 8 ch per head
  int c = l32 * 8;
  float ad = a_d[n * 4 + head];
  float acc[8] = {};
  float psum = 0.f;
  int e = beg;
  for (; e + 8 <= end; e += 8) {
    int s0 = csr[e + half];
    int s1 = csr[e + 2 + half];
    int s2 = csr[e + 4 + half];
    int s3 = csr[e + 6 + half];
    float x0 = a_s[s0 * 4 + head] + ad;
    float x1 = a_s[s1 * 4 + head] + ad;
    float x2 = a_s[s2 * 4 + head] + ad;
    float x3 = a_s[s3 * 4 + head] + ad;
    half8 v0 = *(const half8*)(h + (size_t)s0 * 256 + c);
    half8 v1 = *(const half8*)(h + (size_t)s1 * 256 + c);
    half8 v2 = *(const half8*)(h + (size_t)s2 * 256 + c);
    half8 v3 = *(const half8*)(h + (size_t)s3 * 256 + c);
    x0 = x0 > 0.f ? x0 : x0 * kSlope;
    x1 = x1 > 0.f ? x1 : x1 * kSlope;
    x2 = x2 > 0.f ? x2 : x2 * kSlope;
    x3 = x3 > 0.f ? x3 : x3 * kSlope;
    float p0 = __expf(x0), p1 = __expf(x1);
    float p2 = __expf(x2), p3 = __expf(x3);
    psum += (p0 + p1) + (p2 + p3);
#pragma unroll
    for (int j = 0; j < 8; j++) {
      acc[j] += (float)v0[j] * p0 + (float)v1[j] * p1;
      acc[j] += (float)v2[j] * p2 + (float)v3[j] * p3;
    }
  }
  for (; e + 2 <= end; e += 2) {
    int s0 = csr[e + half];
    float x0 = a_s[s0 * 4 + head] + ad;
    x0 = x0 > 0.f ? x0 : x0 * kSlope;
    float p0 = __expf(x0);
    psum += p0;
    half8 v0 = *(const half8*)(h + (size_t)s0 * 256 + c);
#pragma unroll
    for (int j = 0; j < 8; j++) acc[j] += (float)v0[j] * p0;
  }
  if (e < end && half == 0) {
    int s0 = csr[e];
    float x0 = a_s[s0 * 4 + head] + ad;
    x0 = x0 > 0.f ? x0 : x0 * kSlope;
    float p0 = __expf(x0);
    psum += p0;
    half8 v0 = *(const half8*)(h + (size_t)s0 * 256 + c);
#pragma unroll
    for (int j = 0; j < 8; j++) acc[j] += (float)v0[j] * p0;
  }
  psum += __shfl_xor(psum, 32, 64);
#pragma unroll
  for (int j = 0; j < 8; j++) acc[j] += __shfl_xor(acc[j], 32, 64);
  if (half == 0) {
    float rden = 1.f / (psum + 1e-16f);
    ushortx8 o;
#pragma unroll
    for (int j = 0; j < 8; j++) {
      float v = acc[j] * rden + bias[c + j];
      v = bg[c + j] * (v - bm[c + j]) * rsqrtf(bv[c + j] + kBnEps) + bb[c + j];
      v = v > 0.f ? v : (__expf(v) - 1.f);  // ELU
      o[j] = f2h_us(v);
    }
    *(ushortx8*)(out + (size_t)n * 256 + c) = o;
  }
}

// ---------------- fused softmax+aggregation: wave per node, 40 ch (packed, stride 40) ----

__global__ __launch_bounds__(256) void k_attn_agg40(
    const int* __restrict__ rp, const int* __restrict__ csr, const _Float16* __restrict__ h,
    const float* __restrict__ a_s, const float* __restrict__ a_d, const float* __restrict__ bias,
    float* __restrict__ out, int n_nodes) {
  int wid = (blockIdx.x * blockDim.x + threadIdx.x) >> 6;
  int lane = threadIdx.x & 63;
  if (wid >= n_nodes) return;
  int n = wid;
  int beg = rp[n], end = rp[n + 1];
  float ad = a_d[n];
  int grp = lane >> 3, l8 = lane & 7;
  int c = l8 * 8;  // valid channels only for l8 < 5
  bool act = l8 < 5;
  float acc[8] = {};
  float psum = 0.f;
  for (int base = beg; base < end; base += 16) {
    int e0 = base + grp;
    int e1 = base + 8 + grp;
    if (e0 < end) {
      int s = csr[e0];
      float x = a_s[s] + ad;
      x = x > 0.f ? x : x * kSlope;
      float p = __expf(x);
      psum += p;
      if (act) {
        half8 hv = *(const half8*)(h + (size_t)s * 40 + c);
#pragma unroll
        for (int j = 0; j < 8; j++) acc[j] += (float)hv[j] * p;
      }
    }
    if (e1 < end) {
      int s = csr[e1];
      float x = a_s[s] + ad;
      x = x > 0.f ? x : x * kSlope;
      float p = __expf(x);
      psum += p;
      if (act) {
        half8 hv = *(const half8*)(h + (size_t)s * 40 + c);
#pragma unroll
        for (int j = 0; j < 8; j++) acc[j] += (float)hv[j] * p;
      }
    }
  }
#pragma unroll
  for (int mask = 8; mask <= 32; mask <<= 1) psum += __shfl_xor(psum, mask, 64);
#pragma unroll
  for (int j = 0; j < 8; j++) {
#pragma unroll
    for (int mask = 8; mask <= 32; mask <<= 1) acc[j] += __shfl_xor(acc[j], mask, 64);
  }
  if (lane < 5) {  // channels 0..39
    float rden = 1.f / (psum + 1e-16f);
    float4 o0, o1;
    o0.x = acc[0] * rden + bias[c + 0];
    o0.y = acc[1] * rden + bias[c + 1];
    o0.z = acc[2] * rden + bias[c + 2];
    o0.w = acc[3] * rden + bias[c + 3];
    o1.x = acc[4] * rden + bias[c + 4];
    o1.y = acc[5] * rden + bias[c + 5];
    o1.z = acc[6] * rden + bias[c + 6];
    o1.w = acc[7] * rden + bias[c + 7];
    *(float4*)(out + (size_t)n * 40 + c) = o0;
    *(float4*)(out + (size_t)n * 40 + c + 4) = o1;
  }
}

// ---------------- driver ----------------

extern "C" void kernel_launch(void* const* d_in, const int* in_sizes, int n_in, void* d_out,
                              int out_size, void* d_ws, size_t ws_size, hipStream_t stream) {
  const float* x = (const float*)d_in[0];
  const int* ei = (const int*)d_in[1];
  const float* W0 = (const float*)d_in[2];
  const float* as0 = (const float*)d_in[3];
  const float* ad0 = (const float*)d_in[4];
  const float* b0 = (const float*)d_in[5];
  const float* bg0 = (const float*)d_in[6];
  const float* bb0 = (const float*)d_in[7];
  const float* bm0 = (const float*)d_in[8];
  const float* bv0 = (const float*)d_in[9];
  const float* W1 = (const float*)d_in[10];
  const float* as1 = (const float*)d_in[11];
  const float* ad1 = (const float*)d_in[12];
  const float* b1 = (const float*)d_in[13];
  const float* bg1 = (const float*)d_in[14];
  const float* bb1 = (const float*)d_in[15];
  const float* bm1 = (const float*)d_in[16];
  const float* bv1 = (const float*)d_in[17];
  const float* W2 = (const float*)d_in[18];
  const float* as2 = (const float*)d_in[19];
  const float* ad2 = (const float*)d_in[20];
  const float* b2 = (const float*)d_in[21];
  float* out = (float*)d_out;

  const int E = in_sizes[1] / 2;
  const int* srcIdx = ei;
  const int* dstIdx = ei + E;

  char* p = (char*)d_ws;
  auto alloc = [&](size_t bytes) -> void* {
    void* r = (void*)p;
    p += (bytes + 255) & ~(size_t)255;
    return r;
  };
  int* rp = (int*)alloc((kN + 1) * sizeof(int));
  int* degcur = (int*)alloc((size_t)2 * kN * sizeof(int));  // deg | cursor
  int* deg = degcur;
  int* cur = degcur + kN;
  int* bsum = (int*)alloc(256 * sizeof(int));
  int* csr = (int*)alloc((size_t)E * sizeof(int));
  float* a_s = (float*)alloc((size_t)kN * 4 * sizeof(float));
  float* a_d = (float*)alloc((size_t)kN * 4 * sizeof(float));
  unsigned short* h16 = (unsigned short*)alloc((size_t)kN * 256 * 2);
  unsigned short* act16 = (unsigned short*)alloc((size_t)kN * 256 * 2);
  unsigned short* Wt0 = (unsigned short*)alloc((size_t)256 * 256 * 2);
  unsigned short* Wt1 = (unsigned short*)alloc((size_t)256 * 256 * 2);
  unsigned short* Wt2 = (unsigned short*)alloc((size_t)128 * 256 * 2);

  const int nb = ceil_div(kN, 256);

  // CSR build overlapped with prep/GEMM0:
  hipMemsetAsync(degcur, 0, (size_t)2 * kN * sizeof(int), stream);
  k_prepw_degree<<<1024, 256, 0, stream>>>(dstIdx, deg, E, W0, Wt0, W1, Wt1, W2, Wt2);
  k_scan1<<<nb, 256, 0, stream>>>(deg, rp, bsum, kN);
  k_scan2<<<1, 256, 0, stream>>>(bsum, nb);
  k_scan3<<<nb, 256, 0, stream>>>(rp, bsum, kN);

  const int gemmBlocks = ceil_div(kN, 64);  // 782 full-N BM=64 blocks
  const int sblocks = ceil_div(E, 256);
  k_gemm0_scatter<<<gemmBlocks + sblocks, 256, 0, stream>>>(
      x, Wt0, h16, as0, ad0, a_s, a_d, kN, gemmBlocks, srcIdx, dstIdx, rp, cur, csr, E);

  int wpn_blocks = ceil_div(kN, 4);

  // Layer 0 aggregation
  k_attn_agg256<<<wpn_blocks, 256, 0, stream>>>(rp, csr, (const _Float16*)h16, a_s, a_d, b0, bg0,
                                                bb0, bm0, bv0, act16, kN);

  // Layer 1 (full-N f16 GEMM, BM=64, BK=64)
  k_gemmN_f16<<<gemmBlocks, 256, 0, stream>>>(act16, Wt1, h16, as1, ad1, a_s, a_d, kN);
  k_attn_agg256<<<wpn_blocks, 256, 0, stream>>>(rp, csr, (const _Float16*)h16, a_s, a_d, b1, bg1,
                                                bb1, bm1, bv1, act16, kN);

  // Layer 2: dedicated 40-col GEMM, h2 [N,40] packed (row stride 40) in h16
  k_gemm40<<<gemmBlocks, 256, 0, stream>>>(act16, Wt2, h16, as2, ad2, a_s, a_d, kN);
  k_attn_agg40<<<wpn_blocks, 256, 0, stream>>>(rp, csr, (const _Float16*)h16, a_s, a_d, b2, out,
                                               kN);
}